// Round 3
// baseline (6147.090 us; speedup 1.0000x reference)
//
#include <hip/hip_runtime.h>
#include <hip/hip_bf16.h>

#define N_ 8192
#define E_ 131072

typedef unsigned short u16;
typedef unsigned int u32;

__device__ __forceinline__ float bf2f(u16 u){ return __uint_as_float(((u32)u)<<16); }
__device__ __forceinline__ u16 f2bf(float f){
  u32 u = __float_as_uint(f);
  u32 r = (u + 0x7fffu + ((u>>16)&1u)) >> 16;
  return (u16)r;
}
__device__ __forceinline__ float gelu_f(float x){ return 0.5f*x*(1.f+erff(x*0.70710678118654752f)); }

// ---------------------------------------------------------------------------
// conv1: [N,3,32,32] f32 -> [N,32,16,16] bf16, k5 s2 p2, +bias +BN(eval) +GELU
// block = 2 images x 128 threads; thread = 2 pixels x 32 co
// ---------------------------------------------------------------------------
__global__ __launch_bounds__(256) void conv1_k(const float* __restrict__ patches,
    const float* __restrict__ w, const float* __restrict__ cb,
    const float* __restrict__ bng, const float* __restrict__ bnb,
    u16* __restrict__ h1)
{
  __shared__ float in_l[2*3072];
  __shared__ float w_t[75*32];
  __shared__ float pb[32], ps[32], psh[32];
  int t = threadIdx.x; int blk = blockIdx.x;
  {
    const float4* src = (const float4*)&patches[(size_t)blk*6144];
    float4* dst = (float4*)in_l;
    for (int e=t; e<1536; e+=256) dst[e] = src[e];
  }
  for (int e=t; e<2400; e+=256){ int co=e/75, idx=e-co*75; w_t[idx*32+co] = w[e]; }
  if (t<32){ pb[t]=cb[t]; ps[t]=bng[t]*rsqrtf(1.f+1e-5f); psh[t]=bnb[t]; }
  __syncthreads();
  int img = t>>7, u = t&127;
  int p0 = u, p1 = u+128;
  int oy0 = p0>>4, ox = p0&15, oy1 = p1>>4;
  float acc0[32], acc1[32];
  #pragma unroll
  for (int i=0;i<32;++i){acc0[i]=0.f;acc1[i]=0.f;}
  const float* inb = &in_l[img*3072];
  for (int ci=0; ci<3; ++ci){
    #pragma unroll
    for (int ky=0; ky<5; ++ky){
      int iy0 = oy0*2-2+ky, iy1 = oy1*2-2+ky;
      bool vy0 = (iy0>=0)&&(iy0<32), vy1 = (iy1>=0)&&(iy1<32);
      #pragma unroll
      for (int kx=0; kx<5; ++kx){
        int ix = ox*2-2+kx;
        bool vx = (ix>=0)&&(ix<32);
        float v0 = (vx&&vy0) ? inb[ci*1024+iy0*32+ix] : 0.f;
        float v1 = (vx&&vy1) ? inb[ci*1024+iy1*32+ix] : 0.f;
        const float* wr = &w_t[(ci*25+ky*5+kx)*32];
        #pragma unroll
        for (int cg=0; cg<8; ++cg){
          float4 wv = *(const float4*)&wr[cg*4];
          acc0[cg*4+0]+=v0*wv.x; acc0[cg*4+1]+=v0*wv.y; acc0[cg*4+2]+=v0*wv.z; acc0[cg*4+3]+=v0*wv.w;
          acc1[cg*4+0]+=v1*wv.x; acc1[cg*4+1]+=v1*wv.y; acc1[cg*4+2]+=v1*wv.z; acc1[cg*4+3]+=v1*wv.w;
        }
      }
    }
  }
  int n = blk*2+img;
  u16* ob = &h1[(size_t)n*8192];
  #pragma unroll
  for (int c=0;c<32;++c){
    float y0 = (acc0[c]+pb[c])*ps[c]+psh[c];
    float y1 = (acc1[c]+pb[c])*ps[c]+psh[c];
    ob[c*256+p0] = f2bf(gelu_f(y0));
    ob[c*256+p1] = f2bf(gelu_f(y1));
  }
}

// ---------------------------------------------------------------------------
// generic 3x3 s2 p1 conv (conv2/3/4): bf16 in -> bf16 out (or pooled f32)
// thread = 2 pixels x 8 co; weights staged in ci-chunks
// ---------------------------------------------------------------------------
template<int CI,int CO,int IH,int OH,int IMG,int CHUNK,int POOL>
__global__ __launch_bounds__(256) void convg_k(const u16* __restrict__ hin,
   const float* __restrict__ w, const float* __restrict__ cb, const float* __restrict__ bng,
   const float* __restrict__ bnb, u16* __restrict__ hout, float* __restrict__ pooled)
{
  const int IW=IH, OW=OH;
  const int PIX=OH*OW;
  const int PPG=PIX/2;
  const int TPI=PPG*(CO/8);
  __shared__ u16 in_l[IMG*CI*IH*IW];
  __shared__ float w_l[CHUNK*9*CO];
  __shared__ float pb[CO], ps[CO], psh[CO];
  int t=threadIdx.x, blk=blockIdx.x;
  {
    const u32* src = (const u32*)&hin[(size_t)blk*IMG*CI*IH*IW];
    u32* dst = (u32*)in_l;
    for (int e=t; e<IMG*CI*IH*IW/2; e+=256) dst[e]=src[e];
  }
  for (int e=t; e<CO; e+=256){ pb[e]=cb[e]; ps[e]=bng[e]*rsqrtf(1.f+1e-5f); psh[e]=bnb[e]; }
  int img = t/TPI, u = t - img*TPI;
  int cogrp = u/PPG, pg = u - cogrp*PPG;
  int p0=pg, p1=pg+PPG;
  int oy0=p0/OW, ox0=p0-oy0*OW, oy1=p1/OW, ox1=p1-oy1*OW;
  float acc0[8], acc1[8];
  #pragma unroll
  for (int i=0;i<8;++i){acc0[i]=0.f;acc1[i]=0.f;}
  const u16* inb = &in_l[img*CI*IH*IW];
  for (int cb0=0; cb0<CI; cb0+=CHUNK){
    __syncthreads();
    for (int e=t; e<CHUNK*9*CO; e+=256){
      int idx2 = e/CO; int co = e - idx2*CO;
      int cl = idx2/9; int f = idx2 - cl*9;
      w_l[e] = w[((size_t)co*CI + cb0+cl)*9 + f];
    }
    __syncthreads();
    for (int cl=0; cl<CHUNK; ++cl){
      const u16* ic = &inb[(cb0+cl)*IH*IW];
      #pragma unroll
      for (int ky=0;ky<3;++ky){
        int iy0=oy0*2-1+ky, iy1=oy1*2-1+ky;
        bool vy0 = (iy0>=0)&&(iy0<IH), vy1 = (iy1>=0)&&(iy1<IH);
        #pragma unroll
        for (int kx=0;kx<3;++kx){
          int ix0=ox0*2-1+kx, ix1=ox1*2-1+kx;
          float v0 = (vy0 && ix0>=0 && ix0<IW)? bf2f(ic[iy0*IW+ix0]) : 0.f;
          float v1 = (vy1 && ix1>=0 && ix1<IW)? bf2f(ic[iy1*IW+ix1]) : 0.f;
          const float* wr = &w_l[(cl*9+ky*3+kx)*CO + cogrp*8];
          float4 wa = *(const float4*)wr;
          float4 wb = *(const float4*)(wr+4);
          acc0[0]+=v0*wa.x; acc0[1]+=v0*wa.y; acc0[2]+=v0*wa.z; acc0[3]+=v0*wa.w;
          acc0[4]+=v0*wb.x; acc0[5]+=v0*wb.y; acc0[6]+=v0*wb.z; acc0[7]+=v0*wb.w;
          acc1[0]+=v1*wa.x; acc1[1]+=v1*wa.y; acc1[2]+=v1*wa.z; acc1[3]+=v1*wa.w;
          acc1[4]+=v1*wb.x; acc1[5]+=v1*wb.y; acc1[6]+=v1*wb.z; acc1[7]+=v1*wb.w;
        }
      }
    }
  }
  int n = blk*IMG+img;
  if (!POOL){
    u16* ob = &hout[(size_t)n*CO*PIX];
    #pragma unroll
    for (int c=0;c<8;++c){
      int co = cogrp*8+c;
      float y0 = (acc0[c]+pb[co])*ps[co]+psh[co];
      float y1 = (acc1[c]+pb[co])*ps[co]+psh[co];
      ob[co*PIX+p0] = f2bf(gelu_f(y0));
      ob[co*PIX+p1] = f2bf(gelu_f(y1));
    }
  } else {
    float s[8];
    #pragma unroll
    for (int c=0;c<8;++c){
      int co = cogrp*8+c;
      float y0 = (acc0[c]+pb[co])*ps[co]+psh[co];
      float y1 = (acc1[c]+pb[co])*ps[co]+psh[co];
      s[c] = gelu_f(y0)+gelu_f(y1);
    }
    #pragma unroll
    for (int c=0;c<8;++c){
      float so = __shfl_xor(s[c],1);
      if (pg==0) pooled[(size_t)n*CO + cogrp*8+c] = (s[c]+so)*0.25f;
    }
  }
}

// ---------------------------------------------------------------------------
// fused GEMM: C[8192,256] = A@W^T (+A2@W2^T) + bias (+gated bias2) (+coords)
// MODE 0: plain   MODE 1: +coords cols (pj_w[:,256:258])   MODE 2: dual K
// ---------------------------------------------------------------------------
template<int MODE>
__global__ __launch_bounds__(256) void gemm_k(const float* __restrict__ A, const float* __restrict__ W,
   const float* __restrict__ bias, int ldw,
   const float* __restrict__ A2, const float* __restrict__ W2, const float* __restrict__ bias2,
   const int* __restrict__ deg, const float* __restrict__ coords, const float* __restrict__ pjw,
   float* __restrict__ C)
{
  __shared__ float a_l[32*16];
  __shared__ float b_l[32*256];
  int t=threadIdx.x; int row0=blockIdx.x*16;
  int tm=t>>6, tn=t&63;
  float acc[4][4];
  #pragma unroll
  for (int i=0;i<4;++i)
    #pragma unroll
    for (int j=0;j<4;++j) acc[i][j]=0.f;
  const int passes = (MODE==2)?2:1;
  for (int ps2=0; ps2<passes; ++ps2){
    const float* Ap = ps2? A2:A; const float* Wp = ps2? W2:W; int ld = ps2?256:ldw;
    for (int k0=0;k0<256;k0+=32){
      {
        int e=t*2; int r=e>>5; int k=e&31;
        float2 v = *(const float2*)&Ap[(size_t)(row0+r)*256 + k0+k];
        a_l[k*16+r]=v.x; a_l[(k+1)*16+r]=v.y;
      }
      {
        const float* wr = &Wp[(size_t)t*ld + k0];
        #pragma unroll
        for (int kk=0;kk<32;kk+=2){ float2 v = *(const float2*)&wr[kk]; b_l[kk*256+t]=v.x; b_l[(kk+1)*256+t]=v.y; }
      }
      __syncthreads();
      #pragma unroll
      for (int k=0;k<32;++k){
        float4 av = *(const float4*)&a_l[k*16+tm*4];
        float4 bv = *(const float4*)&b_l[k*256+tn*4];
        float aa[4]={av.x,av.y,av.z,av.w};
        float bb[4]={bv.x,bv.y,bv.z,bv.w};
        #pragma unroll
        for (int i=0;i<4;++i)
          #pragma unroll
          for (int j=0;j<4;++j) acc[i][j]+=aa[i]*bb[j];
      }
      __syncthreads();
    }
  }
  float4 bv = *(const float4*)&bias[tn*4];
  float bias4[4]={bv.x,bv.y,bv.z,bv.w};
  float b24[4]={0.f,0.f,0.f,0.f};
  float cw0[4], cw1[4];
  if (MODE==2){
    float4 b2 = *(const float4*)&bias2[tn*4];
    b24[0]=b2.x; b24[1]=b2.y; b24[2]=b2.z; b24[3]=b2.w;
  }
  if (MODE==1){
    #pragma unroll
    for (int j=0;j<4;++j){ cw0[j]=pjw[(size_t)(tn*4+j)*258+256]; cw1[j]=pjw[(size_t)(tn*4+j)*258+257]; }
  }
  #pragma unroll
  for (int i=0;i<4;++i){
    int r = row0 + tm*4 + i;
    float g2 = 0.f, c0=0.f, c1=0.f;
    if (MODE==2) g2 = (deg[r]>0)?1.f:0.f;
    if (MODE==1){ c0 = coords[(size_t)r*2]*1e-4f; c1 = coords[(size_t)r*2+1]*1e-4f; }
    float4 o;
    float vals[4];
    #pragma unroll
    for (int j=0;j<4;++j){
      float v = acc[i][j] + bias4[j];
      if (MODE==2) v += g2*b24[j];
      if (MODE==1) v += c0*cw0[j] + c1*cw1[j];
      vals[j]=v;
    }
    o.x=vals[0]; o.y=vals[1]; o.z=vals[2]; o.w=vals[3];
    *(float4*)&C[(size_t)r*256 + tn*4] = o;
  }
}

// ---------------------------------------------------------------------------
// LayerNorm variants. MODE 0: out = gelu(LN(tin))  MODE 1: out = LN(x + gelu(tin))
// ---------------------------------------------------------------------------
template<int MODE>
__global__ __launch_bounds__(256) void ln_k(const float* __restrict__ xin, const float* __restrict__ tin,
  const float* __restrict__ g, const float* __restrict__ b, float* __restrict__ out)
{
  int row = blockIdx.x, t = threadIdx.x;
  size_t o = (size_t)row*256+t;
  float v;
  if (MODE==0) v = tin[o];
  else v = xin[o] + gelu_f(tin[o]);
  float s = v, sq = v*v;
  #pragma unroll
  for (int off=32; off>=1; off>>=1){ s += __shfl_xor(s,off); sq += __shfl_xor(sq,off); }
  __shared__ float red[8];
  int wv = t>>6;
  if ((t&63)==0){ red[wv*2]=s; red[wv*2+1]=sq; }
  __syncthreads();
  s = red[0]+red[2]+red[4]+red[6];
  sq = red[1]+red[3]+red[5]+red[7];
  float mu = s*(1.f/256.f);
  float var = sq*(1.f/256.f) - mu*mu;
  float rs = rsqrtf(var + 1e-5f);
  float y = (v-mu)*rs*g[t] + b[t];
  if (MODE==0) y = gelu_f(y);
  out[o] = y;
}

// ---------------------------------------------------------------------------
// CSR build + gather-mean
// ---------------------------------------------------------------------------
__global__ __launch_bounds__(256) void degcount_k(const int* __restrict__ dst, int* __restrict__ deg){
  int e = blockIdx.x*256+threadIdx.x;
  if (e<E_) atomicAdd(&deg[dst[e]],1);
}

__global__ __launch_bounds__(256) void scan_k(const int* __restrict__ deg, int* __restrict__ rowptr,
  float* __restrict__ invd)
{
  __shared__ int part[256];
  int t = threadIdx.x;
  int base = t*32; int run=0; int loc[32];
  #pragma unroll
  for (int i=0;i<32;++i){ loc[i]=run; run += deg[base+i]; }
  part[t]=run;
  __syncthreads();
  for (int off=1; off<256; off<<=1){
    int v = (t>=off)? part[t-off] : 0;
    __syncthreads();
    part[t]+=v;
    __syncthreads();
  }
  int pre = (t>0)? part[t-1] : 0;
  #pragma unroll
  for (int i=0;i<32;++i){
    rowptr[base+i] = pre + loc[i];
    int dv = deg[base+i];
    invd[base+i] = 1.f/fmaxf((float)dv,1.f);
  }
  if (t==255) rowptr[N_] = part[255];
}

__global__ __launch_bounds__(256) void fill_k(const int* __restrict__ src, const int* __restrict__ dst,
  const int* __restrict__ rowptr, int* __restrict__ cursor, int* __restrict__ colidx)
{
  int e = blockIdx.x*256+threadIdx.x;
  if (e<E_){
    int d = dst[e];
    int pos = rowptr[d] + atomicAdd(&cursor[d],1);
    colidx[pos] = src[e];
  }
}

__global__ __launch_bounds__(256) void gather_k(const float* __restrict__ x, const int* __restrict__ rowptr,
    const int* __restrict__ colidx, const float* __restrict__ invd, float* __restrict__ xbar)
{
  int d = blockIdx.x, t = threadIdx.x;
  int j0 = rowptr[d], j1 = rowptr[d+1];
  float s = 0.f;
  for (int j=j0;j<j1;++j){ int c = colidx[j]; s += x[(size_t)c*256+t]; }
  xbar[(size_t)d*256+t] = s*invd[d];
}

// ---------------------------------------------------------------------------
// heads: comp(8) / cmpo(16) / prog(32) from final x
// ---------------------------------------------------------------------------
__global__ __launch_bounds__(64) void heads_k(const float* __restrict__ x,
  const float* __restrict__ cw, const float* __restrict__ cbs,
  const float* __restrict__ mw, const float* __restrict__ mbs,
  const float* __restrict__ pw, const float* __restrict__ pbs,
  float* __restrict__ out)
{
  __shared__ float xr[256];
  int row = blockIdx.x, t = threadIdx.x;
  *(float4*)&xr[t*4] = *(const float4*)&x[(size_t)row*256 + t*4];
  __syncthreads();
  if (t>=56) return;
  const float* w; float bb; float* op;
  if (t<8){ w=&cw[t*256]; bb=cbs[t]; op = out + 2097152 + (size_t)row*8 + t; }
  else if (t<24){ int q=t-8; w=&mw[q*256]; bb=mbs[q]; op = out + 2162688 + (size_t)row*16 + q; }
  else { int q=t-24; w=&pw[q*256]; bb=pbs[q]; op = out + 2293760 + (size_t)row*32 + q; }
  float acc=0.f;
  #pragma unroll 8
  for (int k=0;k<256;k+=4){
    float4 xv=*(const float4*)&xr[k];
    float4 wv=*(const float4*)&w[k];
    acc += xv.x*wv.x + xv.y*wv.y + xv.z*wv.z + xv.w*wv.w;
  }
  *op = acc + bb;
}

// ---------------------------------------------------------------------------
// launch
// ---------------------------------------------------------------------------
extern "C" void kernel_launch(void* const* d_in, const int* in_sizes, int n_in,
                              void* d_out, int out_size, void* d_ws, size_t ws_size,
                              hipStream_t stream)
{
  const float* patches = (const float*)d_in[0];
  const float* coords  = (const float*)d_in[1];
  const int*   eidx    = (const int*)d_in[2];
  const float* c1w = (const float*)d_in[3];  const float* c1b = (const float*)d_in[4];
  const float* b1g = (const float*)d_in[5];  const float* b1b = (const float*)d_in[6];
  const float* c2w = (const float*)d_in[7];  const float* c2b = (const float*)d_in[8];
  const float* b2g = (const float*)d_in[9];  const float* b2b = (const float*)d_in[10];
  const float* c3w = (const float*)d_in[11]; const float* c3b = (const float*)d_in[12];
  const float* b3g = (const float*)d_in[13]; const float* b3b = (const float*)d_in[14];
  const float* c4w = (const float*)d_in[15]; const float* c4b = (const float*)d_in[16];
  const float* b4g = (const float*)d_in[17]; const float* b4b = (const float*)d_in[18];
  const float* encw = (const float*)d_in[19]; const float* encb = (const float*)d_in[20];
  const float* pjw  = (const float*)d_in[21]; const float* pjb  = (const float*)d_in[22];
  const float* plng = (const float*)d_in[23]; const float* plnb = (const float*)d_in[24];
  const float* msgw = (const float*)d_in[25]; const float* msgb = (const float*)d_in[26];
  const float* spw  = (const float*)d_in[27]; const float* spb  = (const float*)d_in[28];
  const float* lng  = (const float*)d_in[29]; const float* lnb  = (const float*)d_in[30];
  const float* compw = (const float*)d_in[31]; const float* compb = (const float*)d_in[32];
  const float* cmpow = (const float*)d_in[33]; const float* cmpob = (const float*)d_in[34];
  const float* progw = (const float*)d_in[35]; const float* progb = (const float*)d_in[36];
  float* out = (float*)d_out;
  char* ws = (char*)d_ws;

  const size_t OFF_H1   = 0;                    // 134217728 bytes (bf16)
  const size_t OFF_H2   = 134217728;            // 67108864
  const size_t OFF_H3   = 201326592;            // 33554432
  const size_t OFF_POOL = 234881024;            // 8388608
  const size_t OFF_IMGF = 243269632;            // 8388608
  const size_t OFF_TBUF = 251658240;            // 8388608
  const size_t OFF_XA   = 260046848;            // 8388608
  const size_t OFF_XB   = 268435456;            // 8388608
  const size_t OFF_XBAR = 276824064;            // 8388608
  const size_t OFF_DEG  = 285212672;            // 32768
  const size_t OFF_ROWP = 285245440;            // 65536
  const size_t OFF_CURS = 285310976;            // 32768
  const size_t OFF_COL  = 285343744;            // 524288
  const size_t OFF_INVD = 285868032;            // 32768

  u16* h1 = (u16*)(ws+OFF_H1);
  u16* h2 = (u16*)(ws+OFF_H2);
  u16* h3 = (u16*)(ws+OFF_H3);
  float* pooled = (float*)(ws+OFF_POOL);
  float* imgf = (float*)(ws+OFF_IMGF);
  float* tbuf = (float*)(ws+OFF_TBUF);
  float* xa = (float*)(ws+OFF_XA);
  float* xb = (float*)(ws+OFF_XB);
  float* xbar = (float*)(ws+OFF_XBAR);
  int* deg = (int*)(ws+OFF_DEG);
  int* rowp = (int*)(ws+OFF_ROWP);
  int* curs = (int*)(ws+OFF_CURS);
  int* col = (int*)(ws+OFF_COL);
  float* invd = (float*)(ws+OFF_INVD);

  hipMemsetAsync(deg, 0, 32768, stream);
  hipMemsetAsync(curs, 0, 32768, stream);

  conv1_k<<<4096,256,0,stream>>>(patches, c1w, c1b, b1g, b1b, h1);
  convg_k<32,64,16,8,1,16,0><<<8192,256,0,stream>>>(h1, c2w, c2b, b2g, b2b, h2, nullptr);
  convg_k<64,128,8,4,2,8,0><<<4096,256,0,stream>>>(h2, c3w, c3b, b3g, b3b, h3, nullptr);
  convg_k<128,256,4,2,4,4,1><<<2048,256,0,stream>>>(h3, c4w, c4b, b4g, b4b, nullptr, pooled);

  gemm_k<0><<<512,256,0,stream>>>(pooled, encw, encb, 256, nullptr,nullptr,nullptr,nullptr,nullptr,nullptr, imgf);
  gemm_k<1><<<512,256,0,stream>>>(imgf, pjw, pjb, 258, nullptr,nullptr,nullptr,nullptr, coords, pjw, tbuf);
  ln_k<0><<<8192,256,0,stream>>>(tbuf, tbuf, plng, plnb, xa);

  degcount_k<<<512,256,0,stream>>>(eidx+E_, deg);
  scan_k<<<1,256,0,stream>>>(deg, rowp, invd);
  fill_k<<<512,256,0,stream>>>(eidx, eidx+E_, rowp, curs, col);

  float* xcur = xa;
  for (int i=0;i<4;++i){
    gather_k<<<8192,256,0,stream>>>(xcur, rowp, col, invd, xbar);
    gemm_k<2><<<512,256,0,stream>>>(xcur, spw+(size_t)i*65536, spb+(size_t)i*256, 256,
                                    xbar, msgw+(size_t)i*65536, msgb+(size_t)i*256,
                                    deg, nullptr, nullptr, tbuf);
    float* xnext = (i==3)? out : ((i&1)? xa : xb);
    ln_k<1><<<8192,256,0,stream>>>(xcur, tbuf, lng+(size_t)i*256, lnb+(size_t)i*256, xnext);
    xcur = xnext;
  }
  heads_k<<<8192,64,0,stream>>>(out, compw, compb, cmpow, cmpob, progw, progb, out);
}

// Round 4
// 4414.477 us; speedup vs baseline: 1.3925x; 1.3925x over previous
//
#include <hip/hip_runtime.h>
#include <hip/hip_bf16.h>

#define N_ 8192
#define E_ 131072

typedef unsigned short u16;
typedef unsigned int u32;

__device__ __forceinline__ float bf2f(u16 u){ return __uint_as_float(((u32)u)<<16); }
__device__ __forceinline__ u16 f2bf(float f){
  u32 u = __float_as_uint(f);
  u32 r = (u + 0x7fffu + ((u>>16)&1u)) >> 16;
  return (u16)r;
}
__device__ __forceinline__ float gelu_f(float x){ return 0.5f*x*(1.f+erff(x*0.70710678118654752f)); }

// ---------------------------------------------------------------------------
// conv1: [N,3,32,32] f32 -> [N,32,16,16] bf16, k5 s2 p2, +bias +BN(eval) +GELU
// block = 256 threads = 1 image x 16-co half; thread = 1 pixel x 16 co
// (prev version: 64 acc/thread -> 256 VGPR cap + 8 GB scratch spill traffic)
// ---------------------------------------------------------------------------
__global__ __launch_bounds__(256) void conv1_k(const float* __restrict__ patches,
    const float* __restrict__ w, const float* __restrict__ cb,
    const float* __restrict__ bng, const float* __restrict__ bnb,
    u16* __restrict__ h1)
{
  __shared__ float in_l[3*1056];      // rows padded to 33 floats (bank spread)
  __shared__ float w_t[75*16];
  __shared__ float pb[16], ps[16], psh[16];
  int t = threadIdx.x;
  int blk = blockIdx.x;
  int img = blk >> 1;
  int half = blk & 1;                 // co base = half*16
  {
    const float* src = &patches[(size_t)img*3072];
    for (int e=t; e<3072; e+=256){
      int ci = e >> 10;
      int rem = e & 1023;
      int iy = rem >> 5, ix = rem & 31;
      in_l[ci*1056 + iy*33 + ix] = src[e];
    }
  }
  for (int e=t; e<1200; e+=256){
    int idx = e >> 4;
    int col = e & 15;
    w_t[e] = w[(size_t)(half*16+col)*75 + idx];
  }
  if (t<16){ int c=half*16+t; pb[t]=cb[c]; ps[t]=bng[c]*rsqrtf(1.f+1e-5f); psh[t]=bnb[c]; }
  __syncthreads();
  int oy = t>>4, ox = t&15;
  float acc[16];
  #pragma unroll
  for (int i=0;i<16;++i) acc[i]=0.f;
  for (int ci=0; ci<3; ++ci){
    const float* inb = &in_l[ci*1056];
    #pragma unroll
    for (int ky=0; ky<5; ++ky){
      int iy = oy*2-2+ky;
      bool vy = (iy>=0)&&(iy<32);
      #pragma unroll
      for (int kx=0; kx<5; ++kx){
        int ix = ox*2-2+kx;
        bool vx = (ix>=0)&&(ix<32);
        float v = (vx&&vy) ? inb[iy*33+ix] : 0.f;
        const float* wr = &w_t[(ci*25+ky*5+kx)*16];
        #pragma unroll
        for (int cg=0; cg<4; ++cg){
          float4 wv = *(const float4*)&wr[cg*4];
          acc[cg*4+0]+=v*wv.x; acc[cg*4+1]+=v*wv.y; acc[cg*4+2]+=v*wv.z; acc[cg*4+3]+=v*wv.w;
        }
      }
    }
  }
  u16* ob = &h1[(size_t)img*8192 + half*4096];
  #pragma unroll
  for (int c=0;c<16;++c){
    float y = (acc[c]+pb[c])*ps[c]+psh[c];
    ob[c*256 + t] = f2bf(gelu_f(y));
  }
}

// ---------------------------------------------------------------------------
// generic 3x3 s2 p1 conv (conv2/3/4): bf16 in -> bf16 out (or pooled f32)
// thread = 2 pixels x 8 co; weights staged in ci-chunks
// ---------------------------------------------------------------------------
template<int CI,int CO,int IH,int OH,int IMG,int CHUNK,int POOL>
__global__ __launch_bounds__(256) void convg_k(const u16* __restrict__ hin,
   const float* __restrict__ w, const float* __restrict__ cb, const float* __restrict__ bng,
   const float* __restrict__ bnb, u16* __restrict__ hout, float* __restrict__ pooled)
{
  const int IW=IH, OW=OH;
  const int PIX=OH*OW;
  const int PPG=PIX/2;
  const int TPI=PPG*(CO/8);
  __shared__ u16 in_l[IMG*CI*IH*IW];
  __shared__ float w_l[CHUNK*9*CO];
  __shared__ float pb[CO], ps[CO], psh[CO];
  int t=threadIdx.x, blk=blockIdx.x;
  {
    const u32* src = (const u32*)&hin[(size_t)blk*IMG*CI*IH*IW];
    u32* dst = (u32*)in_l;
    for (int e=t; e<IMG*CI*IH*IW/2; e+=256) dst[e]=src[e];
  }
  for (int e=t; e<CO; e+=256){ pb[e]=cb[e]; ps[e]=bng[e]*rsqrtf(1.f+1e-5f); psh[e]=bnb[e]; }
  int img = t/TPI, u = t - img*TPI;
  int cogrp = u/PPG, pg = u - cogrp*PPG;
  int p0=pg, p1=pg+PPG;
  int oy0=p0/OW, ox0=p0-oy0*OW, oy1=p1/OW, ox1=p1-oy1*OW;
  float acc0[8], acc1[8];
  #pragma unroll
  for (int i=0;i<8;++i){acc0[i]=0.f;acc1[i]=0.f;}
  const u16* inb = &in_l[img*CI*IH*IW];
  for (int cb0=0; cb0<CI; cb0+=CHUNK){
    __syncthreads();
    for (int e=t; e<CHUNK*9*CO; e+=256){
      int idx2 = e/CO; int co = e - idx2*CO;
      int cl = idx2/9; int f = idx2 - cl*9;
      w_l[e] = w[((size_t)co*CI + cb0+cl)*9 + f];
    }
    __syncthreads();
    for (int cl=0; cl<CHUNK; ++cl){
      const u16* ic = &inb[(cb0+cl)*IH*IW];
      #pragma unroll
      for (int ky=0;ky<3;++ky){
        int iy0=oy0*2-1+ky, iy1=oy1*2-1+ky;
        bool vy0 = (iy0>=0)&&(iy0<IH), vy1 = (iy1>=0)&&(iy1<IH);
        #pragma unroll
        for (int kx=0;kx<3;++kx){
          int ix0=ox0*2-1+kx, ix1=ox1*2-1+kx;
          float v0 = (vy0 && ix0>=0 && ix0<IW)? bf2f(ic[iy0*IW+ix0]) : 0.f;
          float v1 = (vy1 && ix1>=0 && ix1<IW)? bf2f(ic[iy1*IW+ix1]) : 0.f;
          const float* wr = &w_l[(cl*9+ky*3+kx)*CO + cogrp*8];
          float4 wa = *(const float4*)wr;
          float4 wb = *(const float4*)(wr+4);
          acc0[0]+=v0*wa.x; acc0[1]+=v0*wa.y; acc0[2]+=v0*wa.z; acc0[3]+=v0*wa.w;
          acc0[4]+=v0*wb.x; acc0[5]+=v0*wb.y; acc0[6]+=v0*wb.z; acc0[7]+=v0*wb.w;
          acc1[0]+=v1*wa.x; acc1[1]+=v1*wa.y; acc1[2]+=v1*wa.z; acc1[3]+=v1*wa.w;
          acc1[4]+=v1*wb.x; acc1[5]+=v1*wb.y; acc1[6]+=v1*wb.z; acc1[7]+=v1*wb.w;
        }
      }
    }
  }
  int n = blk*IMG+img;
  if (!POOL){
    u16* ob = &hout[(size_t)n*CO*PIX];
    #pragma unroll
    for (int c=0;c<8;++c){
      int co = cogrp*8+c;
      float y0 = (acc0[c]+pb[co])*ps[co]+psh[co];
      float y1 = (acc1[c]+pb[co])*ps[co]+psh[co];
      ob[co*PIX+p0] = f2bf(gelu_f(y0));
      ob[co*PIX+p1] = f2bf(gelu_f(y1));
    }
  } else {
    float s[8];
    #pragma unroll
    for (int c=0;c<8;++c){
      int co = cogrp*8+c;
      float y0 = (acc0[c]+pb[co])*ps[co]+psh[co];
      float y1 = (acc1[c]+pb[co])*ps[co]+psh[co];
      s[c] = gelu_f(y0)+gelu_f(y1);
    }
    #pragma unroll
    for (int c=0;c<8;++c){
      float so = __shfl_xor(s[c],1);
      if (pg==0) pooled[(size_t)n*CO + cogrp*8+c] = (s[c]+so)*0.25f;
    }
  }
}

// ---------------------------------------------------------------------------
// fused GEMM: C[8192,256] = A@W^T (+A2@W2^T) + bias (+gated bias2) (+coords)
// MODE 0: plain   MODE 1: +coords cols (pj_w[:,256:258])   MODE 2: dual K
// ---------------------------------------------------------------------------
template<int MODE>
__global__ __launch_bounds__(256) void gemm_k(const float* __restrict__ A, const float* __restrict__ W,
   const float* __restrict__ bias, int ldw,
   const float* __restrict__ A2, const float* __restrict__ W2, const float* __restrict__ bias2,
   const int* __restrict__ deg, const float* __restrict__ coords, const float* __restrict__ pjw,
   float* __restrict__ C)
{
  __shared__ float a_l[32*16];
  __shared__ float b_l[32*256];
  int t=threadIdx.x; int row0=blockIdx.x*16;
  int tm=t>>6, tn=t&63;
  float acc[4][4];
  #pragma unroll
  for (int i=0;i<4;++i)
    #pragma unroll
    for (int j=0;j<4;++j) acc[i][j]=0.f;
  const int passes = (MODE==2)?2:1;
  for (int ps2=0; ps2<passes; ++ps2){
    const float* Ap = ps2? A2:A; const float* Wp = ps2? W2:W; int ld = ps2?256:ldw;
    for (int k0=0;k0<256;k0+=32){
      {
        int e=t*2; int r=e>>5; int k=e&31;
        float2 v = *(const float2*)&Ap[(size_t)(row0+r)*256 + k0+k];
        a_l[k*16+r]=v.x; a_l[(k+1)*16+r]=v.y;
      }
      {
        const float* wr = &Wp[(size_t)t*ld + k0];
        #pragma unroll
        for (int kk=0;kk<32;kk+=2){ float2 v = *(const float2*)&wr[kk]; b_l[kk*256+t]=v.x; b_l[(kk+1)*256+t]=v.y; }
      }
      __syncthreads();
      #pragma unroll
      for (int k=0;k<32;++k){
        float4 av = *(const float4*)&a_l[k*16+tm*4];
        float4 bv = *(const float4*)&b_l[k*256+tn*4];
        float aa[4]={av.x,av.y,av.z,av.w};
        float bb[4]={bv.x,bv.y,bv.z,bv.w};
        #pragma unroll
        for (int i=0;i<4;++i)
          #pragma unroll
          for (int j=0;j<4;++j) acc[i][j]+=aa[i]*bb[j];
      }
      __syncthreads();
    }
  }
  float4 bv = *(const float4*)&bias[tn*4];
  float bias4[4]={bv.x,bv.y,bv.z,bv.w};
  float b24[4]={0.f,0.f,0.f,0.f};
  float cw0[4], cw1[4];
  if (MODE==2){
    float4 b2 = *(const float4*)&bias2[tn*4];
    b24[0]=b2.x; b24[1]=b2.y; b24[2]=b2.z; b24[3]=b2.w;
  }
  if (MODE==1){
    #pragma unroll
    for (int j=0;j<4;++j){ cw0[j]=pjw[(size_t)(tn*4+j)*258+256]; cw1[j]=pjw[(size_t)(tn*4+j)*258+257]; }
  }
  #pragma unroll
  for (int i=0;i<4;++i){
    int r = row0 + tm*4 + i;
    float g2 = 0.f, c0=0.f, c1=0.f;
    if (MODE==2) g2 = (deg[r]>0)?1.f:0.f;
    if (MODE==1){ c0 = coords[(size_t)r*2]*1e-4f; c1 = coords[(size_t)r*2+1]*1e-4f; }
    float4 o;
    float vals[4];
    #pragma unroll
    for (int j=0;j<4;++j){
      float v = acc[i][j] + bias4[j];
      if (MODE==2) v += g2*b24[j];
      if (MODE==1) v += c0*cw0[j] + c1*cw1[j];
      vals[j]=v;
    }
    o.x=vals[0]; o.y=vals[1]; o.z=vals[2]; o.w=vals[3];
    *(float4*)&C[(size_t)r*256 + tn*4] = o;
  }
}

// ---------------------------------------------------------------------------
// LayerNorm variants. MODE 0: out = gelu(LN(tin))  MODE 1: out = LN(x + gelu(tin))
// ---------------------------------------------------------------------------
template<int MODE>
__global__ __launch_bounds__(256) void ln_k(const float* __restrict__ xin, const float* __restrict__ tin,
  const float* __restrict__ g, const float* __restrict__ b, float* __restrict__ out)
{
  int row = blockIdx.x, t = threadIdx.x;
  size_t o = (size_t)row*256+t;
  float v;
  if (MODE==0) v = tin[o];
  else v = xin[o] + gelu_f(tin[o]);
  float s = v, sq = v*v;
  #pragma unroll
  for (int off=32; off>=1; off>>=1){ s += __shfl_xor(s,off); sq += __shfl_xor(sq,off); }
  __shared__ float red[8];
  int wv = t>>6;
  if ((t&63)==0){ red[wv*2]=s; red[wv*2+1]=sq; }
  __syncthreads();
  s = red[0]+red[2]+red[4]+red[6];
  sq = red[1]+red[3]+red[5]+red[7];
  float mu = s*(1.f/256.f);
  float var = sq*(1.f/256.f) - mu*mu;
  float rs = rsqrtf(var + 1e-5f);
  float y = (v-mu)*rs*g[t] + b[t];
  if (MODE==0) y = gelu_f(y);
  out[o] = y;
}

// ---------------------------------------------------------------------------
// CSR build + gather-mean
// ---------------------------------------------------------------------------
__global__ __launch_bounds__(256) void degcount_k(const int* __restrict__ dst, int* __restrict__ deg){
  int e = blockIdx.x*256+threadIdx.x;
  if (e<E_) atomicAdd(&deg[dst[e]],1);
}

__global__ __launch_bounds__(256) void scan_k(const int* __restrict__ deg, int* __restrict__ rowptr,
  float* __restrict__ invd)
{
  __shared__ int part[256];
  int t = threadIdx.x;
  int base = t*32; int run=0; int loc[32];
  #pragma unroll
  for (int i=0;i<32;++i){ loc[i]=run; run += deg[base+i]; }
  part[t]=run;
  __syncthreads();
  for (int off=1; off<256; off<<=1){
    int v = (t>=off)? part[t-off] : 0;
    __syncthreads();
    part[t]+=v;
    __syncthreads();
  }
  int pre = (t>0)? part[t-1] : 0;
  #pragma unroll
  for (int i=0;i<32;++i){
    rowptr[base+i] = pre + loc[i];
    int dv = deg[base+i];
    invd[base+i] = 1.f/fmaxf((float)dv,1.f);
  }
  if (t==255) rowptr[N_] = part[255];
}

__global__ __launch_bounds__(256) void fill_k(const int* __restrict__ src, const int* __restrict__ dst,
  const int* __restrict__ rowptr, int* __restrict__ cursor, int* __restrict__ colidx)
{
  int e = blockIdx.x*256+threadIdx.x;
  if (e<E_){
    int d = dst[e];
    int pos = rowptr[d] + atomicAdd(&cursor[d],1);
    colidx[pos] = src[e];
  }
}

__global__ __launch_bounds__(256) void gather_k(const float* __restrict__ x, const int* __restrict__ rowptr,
    const int* __restrict__ colidx, const float* __restrict__ invd, float* __restrict__ xbar)
{
  int d = blockIdx.x, t = threadIdx.x;
  int j0 = rowptr[d], j1 = rowptr[d+1];
  float s = 0.f;
  for (int j=j0;j<j1;++j){ int c = colidx[j]; s += x[(size_t)c*256+t]; }
  xbar[(size_t)d*256+t] = s*invd[d];
}

// ---------------------------------------------------------------------------
// heads: comp(8) / cmpo(16) / prog(32) from final x
// ---------------------------------------------------------------------------
__global__ __launch_bounds__(64) void heads_k(const float* __restrict__ x,
  const float* __restrict__ cw, const float* __restrict__ cbs,
  const float* __restrict__ mw, const float* __restrict__ mbs,
  const float* __restrict__ pw, const float* __restrict__ pbs,
  float* __restrict__ out)
{
  __shared__ float xr[256];
  int row = blockIdx.x, t = threadIdx.x;
  *(float4*)&xr[t*4] = *(const float4*)&x[(size_t)row*256 + t*4];
  __syncthreads();
  if (t>=56) return;
  const float* w; float bb; float* op;
  if (t<8){ w=&cw[t*256]; bb=cbs[t]; op = out + 2097152 + (size_t)row*8 + t; }
  else if (t<24){ int q=t-8; w=&mw[q*256]; bb=mbs[q]; op = out + 2162688 + (size_t)row*16 + q; }
  else { int q=t-24; w=&pw[q*256]; bb=pbs[q]; op = out + 2293760 + (size_t)row*32 + q; }
  float acc=0.f;
  #pragma unroll 8
  for (int k=0;k<256;k+=4){
    float4 xv=*(const float4*)&xr[k];
    float4 wv=*(const float4*)&w[k];
    acc += xv.x*wv.x + xv.y*wv.y + xv.z*wv.z + xv.w*wv.w;
  }
  *op = acc + bb;
}

// ---------------------------------------------------------------------------
// launch
// ---------------------------------------------------------------------------
extern "C" void kernel_launch(void* const* d_in, const int* in_sizes, int n_in,
                              void* d_out, int out_size, void* d_ws, size_t ws_size,
                              hipStream_t stream)
{
  const float* patches = (const float*)d_in[0];
  const float* coords  = (const float*)d_in[1];
  const int*   eidx    = (const int*)d_in[2];
  const float* c1w = (const float*)d_in[3];  const float* c1b = (const float*)d_in[4];
  const float* b1g = (const float*)d_in[5];  const float* b1b = (const float*)d_in[6];
  const float* c2w = (const float*)d_in[7];  const float* c2b = (const float*)d_in[8];
  const float* b2g = (const float*)d_in[9];  const float* b2b = (const float*)d_in[10];
  const float* c3w = (const float*)d_in[11]; const float* c3b = (const float*)d_in[12];
  const float* b3g = (const float*)d_in[13]; const float* b3b = (const float*)d_in[14];
  const float* c4w = (const float*)d_in[15]; const float* c4b = (const float*)d_in[16];
  const float* b4g = (const float*)d_in[17]; const float* b4b = (const float*)d_in[18];
  const float* encw = (const float*)d_in[19]; const float* encb = (const float*)d_in[20];
  const float* pjw  = (const float*)d_in[21]; const float* pjb  = (const float*)d_in[22];
  const float* plng = (const float*)d_in[23]; const float* plnb = (const float*)d_in[24];
  const float* msgw = (const float*)d_in[25]; const float* msgb = (const float*)d_in[26];
  const float* spw  = (const float*)d_in[27]; const float* spb  = (const float*)d_in[28];
  const float* lng  = (const float*)d_in[29]; const float* lnb  = (const float*)d_in[30];
  const float* compw = (const float*)d_in[31]; const float* compb = (const float*)d_in[32];
  const float* cmpow = (const float*)d_in[33]; const float* cmpob = (const float*)d_in[34];
  const float* progw = (const float*)d_in[35]; const float* progb = (const float*)d_in[36];
  float* out = (float*)d_out;
  char* ws = (char*)d_ws;

  const size_t OFF_H1   = 0;                    // 134217728 bytes (bf16)
  const size_t OFF_H2   = 134217728;            // 67108864
  const size_t OFF_H3   = 201326592;            // 33554432
  const size_t OFF_POOL = 234881024;            // 8388608
  const size_t OFF_IMGF = 243269632;            // 8388608
  const size_t OFF_TBUF = 251658240;            // 8388608
  const size_t OFF_XA   = 260046848;            // 8388608
  const size_t OFF_XB   = 268435456;            // 8388608
  const size_t OFF_XBAR = 276824064;            // 8388608
  const size_t OFF_DEG  = 285212672;            // 32768
  const size_t OFF_ROWP = 285245440;            // 65536
  const size_t OFF_CURS = 285310976;            // 32768
  const size_t OFF_COL  = 285343744;            // 524288
  const size_t OFF_INVD = 285868032;            // 32768

  u16* h1 = (u16*)(ws+OFF_H1);
  u16* h2 = (u16*)(ws+OFF_H2);
  u16* h3 = (u16*)(ws+OFF_H3);
  float* pooled = (float*)(ws+OFF_POOL);
  float* imgf = (float*)(ws+OFF_IMGF);
  float* tbuf = (float*)(ws+OFF_TBUF);
  float* xa = (float*)(ws+OFF_XA);
  float* xb = (float*)(ws+OFF_XB);
  float* xbar = (float*)(ws+OFF_XBAR);
  int* deg = (int*)(ws+OFF_DEG);
  int* rowp = (int*)(ws+OFF_ROWP);
  int* curs = (int*)(ws+OFF_CURS);
  int* col = (int*)(ws+OFF_COL);
  float* invd = (float*)(ws+OFF_INVD);

  hipMemsetAsync(deg, 0, 32768, stream);
  hipMemsetAsync(curs, 0, 32768, stream);

  conv1_k<<<16384,256,0,stream>>>(patches, c1w, c1b, b1g, b1b, h1);
  convg_k<32,64,16,8,1,16,0><<<8192,256,0,stream>>>(h1, c2w, c2b, b2g, b2b, h2, nullptr);
  convg_k<64,128,8,4,2,8,0><<<4096,256,0,stream>>>(h2, c3w, c3b, b3g, b3b, h3, nullptr);
  convg_k<128,256,4,2,4,4,1><<<2048,256,0,stream>>>(h3, c4w, c4b, b4g, b4b, nullptr, pooled);

  gemm_k<0><<<512,256,0,stream>>>(pooled, encw, encb, 256, nullptr,nullptr,nullptr,nullptr,nullptr,nullptr, imgf);
  gemm_k<1><<<512,256,0,stream>>>(imgf, pjw, pjb, 258, nullptr,nullptr,nullptr,nullptr, coords, pjw, tbuf);
  ln_k<0><<<8192,256,0,stream>>>(tbuf, tbuf, plng, plnb, xa);

  degcount_k<<<512,256,0,stream>>>(eidx+E_, deg);
  scan_k<<<1,256,0,stream>>>(deg, rowp, invd);
  fill_k<<<512,256,0,stream>>>(eidx, eidx+E_, rowp, curs, col);

  float* xcur = xa;
  for (int i=0;i<4;++i){
    gather_k<<<8192,256,0,stream>>>(xcur, rowp, col, invd, xbar);
    gemm_k<2><<<512,256,0,stream>>>(xcur, spw+(size_t)i*65536, spb+(size_t)i*256, 256,
                                    xbar, msgw+(size_t)i*65536, msgb+(size_t)i*256,
                                    deg, nullptr, nullptr, tbuf);
    float* xnext = (i==3)? out : ((i&1)? xa : xb);
    ln_k<1><<<8192,256,0,stream>>>(xcur, tbuf, lng+(size_t)i*256, lnb+(size_t)i*256, xnext);
    xcur = xnext;
  }
  heads_k<<<8192,64,0,stream>>>(out, compw, compb, cmpow, cmpob, progw, progb, out);
}

// Round 5
// 3282.106 us; speedup vs baseline: 1.8729x; 1.3450x over previous
//
#include <hip/hip_runtime.h>
#include <hip/hip_bf16.h>

#define N_ 8192
#define E_ 131072

typedef unsigned short u16;
typedef unsigned int u32;

__device__ __forceinline__ float bf2f(u16 u){ return __uint_as_float(((u32)u)<<16); }
__device__ __forceinline__ u16 f2bf(float f){
  u32 u = __float_as_uint(f);
  u32 r = (u + 0x7fffu + ((u>>16)&1u)) >> 16;
  return (u16)r;
}
__device__ __forceinline__ float gelu_f(float x){ return 0.5f*x*(1.f+erff(x*0.70710678118654752f)); }

// ---------------------------------------------------------------------------
// weight transpose: [CO][K9] -> [K9][CO]  (one-time, coalesced stores)
// ---------------------------------------------------------------------------
__global__ __launch_bounds__(256) void wtrans_k(const float* __restrict__ src,
    float* __restrict__ dst, int K9, int CO, int total)
{
  int e = blockIdx.x*256 + threadIdx.x;
  if (e < total){
    int idx = e / CO, co = e - idx*CO;
    dst[e] = src[(size_t)co*K9 + idx];
  }
}

// ---------------------------------------------------------------------------
// conv1: [N,3,32,32] f32 -> [N,32,16,16] bf16, k5 s2 p2, +bias +BN(eval) +GELU
// block = 256 threads = 1 image x 16-co half; thread = 1 pixel x 16 co
// ---------------------------------------------------------------------------
__global__ __launch_bounds__(256) void conv1_k(const float* __restrict__ patches,
    const float* __restrict__ wT, const float* __restrict__ cb,
    const float* __restrict__ bng, const float* __restrict__ bnb,
    u16* __restrict__ h1)
{
  __shared__ float in_l[3*1056];      // rows padded to 33 floats (bank spread)
  __shared__ float w_t[75*16];
  __shared__ float pb[16], ps[16], psh[16];
  int t = threadIdx.x;
  int blk = blockIdx.x;
  int img = blk >> 1;
  int half = blk & 1;                 // co base = half*16
  {
    const float* src = &patches[(size_t)img*3072];
    for (int e=t; e<3072; e+=256){
      int ci = e >> 10;
      int rem = e & 1023;
      int iy = rem >> 5, ix = rem & 31;
      in_l[ci*1056 + iy*33 + ix] = src[e];
    }
  }
  for (int e=t; e<1200; e+=256){
    w_t[e] = wT[(e>>4)*32 + half*16 + (e&15)];
  }
  if (t<16){ int c=half*16+t; pb[t]=cb[c]; ps[t]=bng[c]*rsqrtf(1.f+1e-5f); psh[t]=bnb[c]; }
  __syncthreads();
  int oy = t>>4, ox = t&15;
  float acc[16];
  #pragma unroll
  for (int i=0;i<16;++i) acc[i]=0.f;
  for (int ci=0; ci<3; ++ci){
    const float* inb = &in_l[ci*1056];
    #pragma unroll
    for (int ky=0; ky<5; ++ky){
      int iy = oy*2-2+ky;
      bool vy = (iy>=0)&&(iy<32);
      #pragma unroll
      for (int kx=0; kx<5; ++kx){
        int ix = ox*2-2+kx;
        bool vx = (ix>=0)&&(ix<32);
        float v = (vx&&vy) ? inb[iy*33+ix] : 0.f;
        const float* wr = &w_t[(ci*25+ky*5+kx)*16];
        #pragma unroll
        for (int cg=0; cg<4; ++cg){
          float4 wv = *(const float4*)&wr[cg*4];
          acc[cg*4+0]+=v*wv.x; acc[cg*4+1]+=v*wv.y; acc[cg*4+2]+=v*wv.z; acc[cg*4+3]+=v*wv.w;
        }
      }
    }
  }
  u16* ob = &h1[(size_t)img*8192 + half*4096];
  #pragma unroll
  for (int c=0;c<16;++c){
    float y = (acc[c]+pb[c])*ps[c]+psh[c];
    ob[c*256 + t] = f2bf(gelu_f(y));
  }
}

// ---------------------------------------------------------------------------
// generic 3x3 s2 p1 conv (conv2/3/4): bf16 in -> bf16 out (or pooled f32)
// thread = 2 pixels x 8 co; weights pre-transposed to [ci*9+f][co]
// ---------------------------------------------------------------------------
template<int CI,int CO,int IH,int OH,int IMG,int CHUNK,int POOL>
__global__ __launch_bounds__(256) void convg_k(const u16* __restrict__ hin,
   const float* __restrict__ wT, const float* __restrict__ cb, const float* __restrict__ bng,
   const float* __restrict__ bnb, u16* __restrict__ hout, float* __restrict__ pooled)
{
  const int IW=IH, OW=OH;
  const int PIX=OH*OW;
  const int PPG=PIX/2;
  const int TPI=PPG*(CO/8);
  __shared__ u16 in_l[IMG*CI*IH*IW];
  __shared__ float w_l[CHUNK*9*CO];
  __shared__ float pb[CO], ps[CO], psh[CO];
  int t=threadIdx.x, blk=blockIdx.x;
  {
    const u32* src = (const u32*)&hin[(size_t)blk*IMG*CI*IH*IW];
    u32* dst = (u32*)in_l;
    for (int e=t; e<IMG*CI*IH*IW/2; e+=256) dst[e]=src[e];
  }
  for (int e=t; e<CO; e+=256){ pb[e]=cb[e]; ps[e]=bng[e]*rsqrtf(1.f+1e-5f); psh[e]=bnb[e]; }
  int img = t/TPI, u = t - img*TPI;
  int cogrp = u/PPG, pg = u - cogrp*PPG;
  int p0=pg, p1=pg+PPG;
  int oy0=p0/OW, ox0=p0-oy0*OW, oy1=p1/OW, ox1=p1-oy1*OW;
  float acc0[8], acc1[8];
  #pragma unroll
  for (int i=0;i<8;++i){acc0[i]=0.f;acc1[i]=0.f;}
  const u16* inb = &in_l[img*CI*IH*IW];
  for (int cb0=0; cb0<CI; cb0+=CHUNK){
    __syncthreads();
    {
      // coalesced float4 copy of contiguous rows [cb0*9 .. (cb0+CHUNK)*9) x CO
      const float4* s4 = (const float4*)&wT[(size_t)cb0*9*CO];
      float4* d4 = (float4*)w_l;
      #pragma unroll
      for (int e=t; e<CHUNK*9*CO/4; e+=256) d4[e] = s4[e];
    }
    __syncthreads();
    for (int cl=0; cl<CHUNK; ++cl){
      const u16* ic = &inb[(cb0+cl)*IH*IW];
      #pragma unroll
      for (int ky=0;ky<3;++ky){
        int iy0=oy0*2-1+ky, iy1=oy1*2-1+ky;
        bool vy0 = (iy0>=0)&&(iy0<IH), vy1 = (iy1>=0)&&(iy1<IH);
        #pragma unroll
        for (int kx=0;kx<3;++kx){
          int ix0=ox0*2-1+kx, ix1=ox1*2-1+kx;
          float v0 = (vy0 && ix0>=0 && ix0<IW)? bf2f(ic[iy0*IW+ix0]) : 0.f;
          float v1 = (vy1 && ix1>=0 && ix1<IW)? bf2f(ic[iy1*IW+ix1]) : 0.f;
          const float* wr = &w_l[(cl*9+ky*3+kx)*CO + cogrp*8];
          float4 wa = *(const float4*)wr;
          float4 wb = *(const float4*)(wr+4);
          acc0[0]+=v0*wa.x; acc0[1]+=v0*wa.y; acc0[2]+=v0*wa.z; acc0[3]+=v0*wa.w;
          acc0[4]+=v0*wb.x; acc0[5]+=v0*wb.y; acc0[6]+=v0*wb.z; acc0[7]+=v0*wb.w;
          acc1[0]+=v1*wa.x; acc1[1]+=v1*wa.y; acc1[2]+=v1*wa.z; acc1[3]+=v1*wa.w;
          acc1[4]+=v1*wb.x; acc1[5]+=v1*wb.y; acc1[6]+=v1*wb.z; acc1[7]+=v1*wb.w;
        }
      }
    }
  }
  int n = blk*IMG+img;
  if (!POOL){
    u16* ob = &hout[(size_t)n*CO*PIX];
    #pragma unroll
    for (int c=0;c<8;++c){
      int co = cogrp*8+c;
      float y0 = (acc0[c]+pb[co])*ps[co]+psh[co];
      float y1 = (acc1[c]+pb[co])*ps[co]+psh[co];
      ob[co*PIX+p0] = f2bf(gelu_f(y0));
      ob[co*PIX+p1] = f2bf(gelu_f(y1));
    }
  } else {
    float s[8];
    #pragma unroll
    for (int c=0;c<8;++c){
      int co = cogrp*8+c;
      float y0 = (acc0[c]+pb[co])*ps[co]+psh[co];
      float y1 = (acc1[c]+pb[co])*ps[co]+psh[co];
      s[c] = gelu_f(y0)+gelu_f(y1);
    }
    #pragma unroll
    for (int c=0;c<8;++c){
      float so = __shfl_xor(s[c],1);
      if (pg==0) pooled[(size_t)n*CO + cogrp*8+c] = (s[c]+so)*0.25f;
    }
  }
}

// ---------------------------------------------------------------------------
// fused GEMM: C[8192,256] = A@W^T (+A2@W2^T) + bias (+gated bias2) (+coords)
// MODE 0: plain   MODE 1: +coords cols (pj_w[:,256:258])   MODE 2: dual K
// ---------------------------------------------------------------------------
template<int MODE>
__global__ __launch_bounds__(256) void gemm_k(const float* __restrict__ A, const float* __restrict__ W,
   const float* __restrict__ bias, int ldw,
   const float* __restrict__ A2, const float* __restrict__ W2, const float* __restrict__ bias2,
   const int* __restrict__ deg, const float* __restrict__ coords, const float* __restrict__ pjw,
   float* __restrict__ C)
{
  __shared__ float a_l[32*16];
  __shared__ float b_l[32*256];
  int t=threadIdx.x; int row0=blockIdx.x*16;
  int tm=t>>6, tn=t&63;
  float acc[4][4];
  #pragma unroll
  for (int i=0;i<4;++i)
    #pragma unroll
    for (int j=0;j<4;++j) acc[i][j]=0.f;
  const int passes = (MODE==2)?2:1;
  for (int ps2=0; ps2<passes; ++ps2){
    const float* Ap = ps2? A2:A; const float* Wp = ps2? W2:W; int ld = ps2?256:ldw;
    for (int k0=0;k0<256;k0+=32){
      {
        int e=t*2; int r=e>>5; int k=e&31;
        float2 v = *(const float2*)&Ap[(size_t)(row0+r)*256 + k0+k];
        a_l[k*16+r]=v.x; a_l[(k+1)*16+r]=v.y;
      }
      {
        const float* wr = &Wp[(size_t)t*ld + k0];
        #pragma unroll
        for (int kk=0;kk<32;kk+=2){ float2 v = *(const float2*)&wr[kk]; b_l[kk*256+t]=v.x; b_l[(kk+1)*256+t]=v.y; }
      }
      __syncthreads();
      #pragma unroll
      for (int k=0;k<32;++k){
        float4 av = *(const float4*)&a_l[k*16+tm*4];
        float4 bv = *(const float4*)&b_l[k*256+tn*4];
        float aa[4]={av.x,av.y,av.z,av.w};
        float bb[4]={bv.x,bv.y,bv.z,bv.w};
        #pragma unroll
        for (int i=0;i<4;++i)
          #pragma unroll
          for (int j=0;j<4;++j) acc[i][j]+=aa[i]*bb[j];
      }
      __syncthreads();
    }
  }
  float4 bv = *(const float4*)&bias[tn*4];
  float bias4[4]={bv.x,bv.y,bv.z,bv.w};
  float b24[4]={0.f,0.f,0.f,0.f};
  float cw0[4], cw1[4];
  if (MODE==2){
    float4 b2 = *(const float4*)&bias2[tn*4];
    b24[0]=b2.x; b24[1]=b2.y; b24[2]=b2.z; b24[3]=b2.w;
  }
  if (MODE==1){
    #pragma unroll
    for (int j=0;j<4;++j){ cw0[j]=pjw[(size_t)(tn*4+j)*258+256]; cw1[j]=pjw[(size_t)(tn*4+j)*258+257]; }
  }
  #pragma unroll
  for (int i=0;i<4;++i){
    int r = row0 + tm*4 + i;
    float g2 = 0.f, c0=0.f, c1=0.f;
    if (MODE==2) g2 = (deg[r]>0)?1.f:0.f;
    if (MODE==1){ c0 = coords[(size_t)r*2]*1e-4f; c1 = coords[(size_t)r*2+1]*1e-4f; }
    float4 o;
    float vals[4];
    #pragma unroll
    for (int j=0;j<4;++j){
      float v = acc[i][j] + bias4[j];
      if (MODE==2) v += g2*b24[j];
      if (MODE==1) v += c0*cw0[j] + c1*cw1[j];
      vals[j]=v;
    }
    o.x=vals[0]; o.y=vals[1]; o.z=vals[2]; o.w=vals[3];
    *(float4*)&C[(size_t)r*256 + tn*4] = o;
  }
}

// ---------------------------------------------------------------------------
// LayerNorm variants. MODE 0: out = gelu(LN(tin))  MODE 1: out = LN(x + gelu(tin))
// ---------------------------------------------------------------------------
template<int MODE>
__global__ __launch_bounds__(256) void ln_k(const float* __restrict__ xin, const float* __restrict__ tin,
  const float* __restrict__ g, const float* __restrict__ b, float* __restrict__ out)
{
  int row = blockIdx.x, t = threadIdx.x;
  size_t o = (size_t)row*256+t;
  float v;
  if (MODE==0) v = tin[o];
  else v = xin[o] + gelu_f(tin[o]);
  float s = v, sq = v*v;
  #pragma unroll
  for (int off=32; off>=1; off>>=1){ s += __shfl_xor(s,off); sq += __shfl_xor(sq,off); }
  __shared__ float red[8];
  int wv = t>>6;
  if ((t&63)==0){ red[wv*2]=s; red[wv*2+1]=sq; }
  __syncthreads();
  s = red[0]+red[2]+red[4]+red[6];
  sq = red[1]+red[3]+red[5]+red[7];
  float mu = s*(1.f/256.f);
  float var = sq*(1.f/256.f) - mu*mu;
  float rs = rsqrtf(var + 1e-5f);
  float y = (v-mu)*rs*g[t] + b[t];
  if (MODE==0) y = gelu_f(y);
  out[o] = y;
}

// ---------------------------------------------------------------------------
// CSR build + gather-mean
// ---------------------------------------------------------------------------
__global__ __launch_bounds__(256) void degcount_k(const int* __restrict__ dst, int* __restrict__ deg){
  int e = blockIdx.x*256+threadIdx.x;
  if (e<E_) atomicAdd(&deg[dst[e]],1);
}

__global__ __launch_bounds__(256) void scan_k(const int* __restrict__ deg, int* __restrict__ rowptr,
  float* __restrict__ invd)
{
  __shared__ int part[256];
  int t = threadIdx.x;
  int base = t*32; int run=0; int loc[32];
  #pragma unroll
  for (int i=0;i<32;++i){ loc[i]=run; run += deg[base+i]; }
  part[t]=run;
  __syncthreads();
  for (int off=1; off<256; off<<=1){
    int v = (t>=off)? part[t-off] : 0;
    __syncthreads();
    part[t]+=v;
    __syncthreads();
  }
  int pre = (t>0)? part[t-1] : 0;
  #pragma unroll
  for (int i=0;i<32;++i){
    rowptr[base+i] = pre + loc[i];
    int dv = deg[base+i];
    invd[base+i] = 1.f/fmaxf((float)dv,1.f);
  }
  if (t==255) rowptr[N_] = part[255];
}

__global__ __launch_bounds__(256) void fill_k(const int* __restrict__ src, const int* __restrict__ dst,
  const int* __restrict__ rowptr, int* __restrict__ cursor, int* __restrict__ colidx)
{
  int e = blockIdx.x*256+threadIdx.x;
  if (e<E_){
    int d = dst[e];
    int pos = rowptr[d] + atomicAdd(&cursor[d],1);
    colidx[pos] = src[e];
  }
}

__global__ __launch_bounds__(256) void gather_k(const float* __restrict__ x, const int* __restrict__ rowptr,
    const int* __restrict__ colidx, const float* __restrict__ invd, float* __restrict__ xbar)
{
  int d = blockIdx.x, t = threadIdx.x;
  int j0 = rowptr[d], j1 = rowptr[d+1];
  float s = 0.f;
  for (int j=j0;j<j1;++j){ int c = colidx[j]; s += x[(size_t)c*256+t]; }
  xbar[(size_t)d*256+t] = s*invd[d];
}

// ---------------------------------------------------------------------------
// heads: comp(8) / cmpo(16) / prog(32) from final x
// ---------------------------------------------------------------------------
__global__ __launch_bounds__(64) void heads_k(const float* __restrict__ x,
  const float* __restrict__ cw, const float* __restrict__ cbs,
  const float* __restrict__ mw, const float* __restrict__ mbs,
  const float* __restrict__ pw, const float* __restrict__ pbs,
  float* __restrict__ out)
{
  __shared__ float xr[256];
  int row = blockIdx.x, t = threadIdx.x;
  *(float4*)&xr[t*4] = *(const float4*)&x[(size_t)row*256 + t*4];
  __syncthreads();
  if (t>=56) return;
  const float* w; float bb; float* op;
  if (t<8){ w=&cw[t*256]; bb=cbs[t]; op = out + 2097152 + (size_t)row*8 + t; }
  else if (t<24){ int q=t-8; w=&mw[q*256]; bb=mbs[q]; op = out + 2162688 + (size_t)row*16 + q; }
  else { int q=t-24; w=&pw[q*256]; bb=pbs[q]; op = out + 2293760 + (size_t)row*32 + q; }
  float acc=0.f;
  #pragma unroll 8
  for (int k=0;k<256;k+=4){
    float4 xv=*(const float4*)&xr[k];
    float4 wv=*(const float4*)&w[k];
    acc += xv.x*wv.x + xv.y*wv.y + xv.z*wv.z + xv.w*wv.w;
  }
  *op = acc + bb;
}

// ---------------------------------------------------------------------------
// launch
// ---------------------------------------------------------------------------
extern "C" void kernel_launch(void* const* d_in, const int* in_sizes, int n_in,
                              void* d_out, int out_size, void* d_ws, size_t ws_size,
                              hipStream_t stream)
{
  const float* patches = (const float*)d_in[0];
  const float* coords  = (const float*)d_in[1];
  const int*   eidx    = (const int*)d_in[2];
  const float* c1w = (const float*)d_in[3];  const float* c1b = (const float*)d_in[4];
  const float* b1g = (const float*)d_in[5];  const float* b1b = (const float*)d_in[6];
  const float* c2w = (const float*)d_in[7];  const float* c2b = (const float*)d_in[8];
  const float* b2g = (const float*)d_in[9];  const float* b2b = (const float*)d_in[10];
  const float* c3w = (const float*)d_in[11]; const float* c3b = (const float*)d_in[12];
  const float* b3g = (const float*)d_in[13]; const float* b3b = (const float*)d_in[14];
  const float* c4w = (const float*)d_in[15]; const float* c4b = (const float*)d_in[16];
  const float* b4g = (const float*)d_in[17]; const float* b4b = (const float*)d_in[18];
  const float* encw = (const float*)d_in[19]; const float* encb = (const float*)d_in[20];
  const float* pjw  = (const float*)d_in[21]; const float* pjb  = (const float*)d_in[22];
  const float* plng = (const float*)d_in[23]; const float* plnb = (const float*)d_in[24];
  const float* msgw = (const float*)d_in[25]; const float* msgb = (const float*)d_in[26];
  const float* spw  = (const float*)d_in[27]; const float* spb  = (const float*)d_in[28];
  const float* lng  = (const float*)d_in[29]; const float* lnb  = (const float*)d_in[30];
  const float* compw = (const float*)d_in[31]; const float* compb = (const float*)d_in[32];
  const float* cmpow = (const float*)d_in[33]; const float* cmpob = (const float*)d_in[34];
  const float* progw = (const float*)d_in[35]; const float* progb = (const float*)d_in[36];
  float* out = (float*)d_out;
  char* ws = (char*)d_ws;

  const size_t OFF_H1   = 0;                    // 134217728 bytes (bf16)
  const size_t OFF_H2   = 134217728;            // 67108864
  const size_t OFF_H3   = 201326592;            // 33554432
  const size_t OFF_POOL = 234881024;            // 8388608
  const size_t OFF_IMGF = 243269632;            // 8388608
  const size_t OFF_TBUF = 251658240;            // 8388608
  const size_t OFF_XA   = 260046848;            // 8388608
  const size_t OFF_XB   = 268435456;            // 8388608
  const size_t OFF_XBAR = 276824064;            // 8388608
  const size_t OFF_DEG  = 285212672;            // 32768
  const size_t OFF_ROWP = 285245440;            // 65536
  const size_t OFF_CURS = 285310976;            // 32768
  const size_t OFF_COL  = 285343744;            // 524288
  const size_t OFF_INVD = 285868032;            // 32768
  // transposed conv weights live in the (not-yet-used) TBUF window; dead after conv4
  const size_t OFF_WT4  = OFF_TBUF;             // 1179648
  const size_t OFF_WT3  = OFF_TBUF + 1179648;   // 294912
  const size_t OFF_WT2  = OFF_TBUF + 1474560;   // 73728
  const size_t OFF_WT1  = OFF_TBUF + 1548288;   // 9600

  u16* h1 = (u16*)(ws+OFF_H1);
  u16* h2 = (u16*)(ws+OFF_H2);
  u16* h3 = (u16*)(ws+OFF_H3);
  float* pooled = (float*)(ws+OFF_POOL);
  float* imgf = (float*)(ws+OFF_IMGF);
  float* tbuf = (float*)(ws+OFF_TBUF);
  float* xa = (float*)(ws+OFF_XA);
  float* xb = (float*)(ws+OFF_XB);
  float* xbar = (float*)(ws+OFF_XBAR);
  int* deg = (int*)(ws+OFF_DEG);
  int* rowp = (int*)(ws+OFF_ROWP);
  int* curs = (int*)(ws+OFF_CURS);
  int* col = (int*)(ws+OFF_COL);
  float* invd = (float*)(ws+OFF_INVD);
  float* wt1 = (float*)(ws+OFF_WT1);
  float* wt2 = (float*)(ws+OFF_WT2);
  float* wt3 = (float*)(ws+OFF_WT3);
  float* wt4 = (float*)(ws+OFF_WT4);

  hipMemsetAsync(deg, 0, 32768, stream);
  hipMemsetAsync(curs, 0, 32768, stream);

  wtrans_k<<<(2400+255)/256,256,0,stream>>>(c1w, wt1, 75, 32, 2400);
  wtrans_k<<<(18432+255)/256,256,0,stream>>>(c2w, wt2, 288, 64, 18432);
  wtrans_k<<<(73728+255)/256,256,0,stream>>>(c3w, wt3, 576, 128, 73728);
  wtrans_k<<<(294912+255)/256,256,0,stream>>>(c4w, wt4, 1152, 256, 294912);

  conv1_k<<<16384,256,0,stream>>>(patches, wt1, c1b, b1g, b1b, h1);
  convg_k<32,64,16,8,1,16,0><<<8192,256,0,stream>>>(h1, wt2, c2b, b2g, b2b, h2, nullptr);
  convg_k<64,128,8,4,2,8,0><<<4096,256,0,stream>>>(h2, wt3, c3b, b3g, b3b, h3, nullptr);
  convg_k<128,256,4,2,4,4,1><<<2048,256,0,stream>>>(h3, wt4, c4b, b4g, b4b, nullptr, pooled);

  gemm_k<0><<<512,256,0,stream>>>(pooled, encw, encb, 256, nullptr,nullptr,nullptr,nullptr,nullptr,nullptr, imgf);
  gemm_k<1><<<512,256,0,stream>>>(imgf, pjw, pjb, 258, nullptr,nullptr,nullptr,nullptr, coords, pjw, tbuf);
  ln_k<0><<<8192,256,0,stream>>>(tbuf, tbuf, plng, plnb, xa);

  degcount_k<<<512,256,0,stream>>>(eidx+E_, deg);
  scan_k<<<1,256,0,stream>>>(deg, rowp, invd);
  fill_k<<<512,256,0,stream>>>(eidx, eidx+E_, rowp, curs, col);

  float* xcur = xa;
  for (int i=0;i<4;++i){
    gather_k<<<8192,256,0,stream>>>(xcur, rowp, col, invd, xbar);
    gemm_k<2><<<512,256,0,stream>>>(xcur, spw+(size_t)i*65536, spb+(size_t)i*256, 256,
                                    xbar, msgw+(size_t)i*65536, msgb+(size_t)i*256,
                                    deg, nullptr, nullptr, tbuf);
    float* xnext = (i==3)? out : ((i&1)? xa : xb);
    ln_k<1><<<8192,256,0,stream>>>(xcur, tbuf, lng+(size_t)i*256, lnb+(size_t)i*256, xnext);
    xcur = xnext;
  }
  heads_k<<<8192,64,0,stream>>>(out, compw, compb, cmpow, cmpob, progw, progb, out);
}

// Round 6
// 1783.723 us; speedup vs baseline: 3.4462x; 1.8400x over previous
//
#include <hip/hip_runtime.h>
#include <hip/hip_bf16.h>

#define N_ 8192
#define E_ 131072

typedef unsigned short u16;
typedef unsigned int u32;
typedef __attribute__((ext_vector_type(8))) short bf16x8;
typedef __attribute__((ext_vector_type(4))) float f32x4;

__device__ __forceinline__ float bf2f(u16 u){ return __uint_as_float(((u32)u)<<16); }
__device__ __forceinline__ u16 f2bf(float f){
  u32 u = __float_as_uint(f);
  u32 r = (u + 0x7fffu + ((u>>16)&1u)) >> 16;
  return (u16)r;
}
__device__ __forceinline__ float gelu_f(float x){ return 0.5f*x*(1.f+erff(x*0.70710678118654752f)); }

// XOR-swizzle: permute byte bits 4-6 keyed on bits >=7 (involution; 16B-chunk preserving)
template<int S1,int S2>
__device__ __forceinline__ u32 swz(u32 b){
  if (S1==0) return b;
  u32 k = b >> S1;
  if (S2) k ^= (b >> S2);
  return b ^ ((k & 7u) << 4);
}

// ---------------------------------------------------------------------------
// weight transpose (conv1, f32): [CO][K9] -> [K9][CO]
// ---------------------------------------------------------------------------
__global__ __launch_bounds__(256) void wtrans_k(const float* __restrict__ src,
    float* __restrict__ dst, int K9, int CO, int total)
{
  int e = blockIdx.x*256 + threadIdx.x;
  if (e < total){
    int idx = e / CO, co = e - idx*CO;
    dst[e] = src[(size_t)co*K9 + idx];
  }
}

// ---------------------------------------------------------------------------
// weight pack (conv2/3/4): f32 OIHW [co][ci][tap9] -> bf16 [tap][co][ci]
// ---------------------------------------------------------------------------
__global__ __launch_bounds__(256) void wpack_k(const float* __restrict__ src,
    u16* __restrict__ dst, int CO, int CI, int total)
{
  int e = blockIdx.x*256 + threadIdx.x;
  if (e < total){
    int tap = e / (CO*CI);
    int rem = e - tap*CO*CI;
    int co = rem / CI, ci = rem - co*CI;
    dst[e] = f2bf(src[((size_t)co*CI + ci)*9 + tap]);
  }
}

// ---------------------------------------------------------------------------
// conv1: [N,3,32,32] f32 -> h1 NHWC [N][256 pix][32 ci] bf16, k5 s2 p2 +BN+GELU
// block = 256 threads = 1 image x 16-co half; thread = 1 pixel x 16 co
// ---------------------------------------------------------------------------
__global__ __launch_bounds__(256) void conv1_k(const float* __restrict__ patches,
    const float* __restrict__ wT, const float* __restrict__ cb,
    const float* __restrict__ bng, const float* __restrict__ bnb,
    u16* __restrict__ h1)
{
  __shared__ float in_l[3*1056];
  __shared__ float w_t[75*16];
  __shared__ float pb[16], ps[16], psh[16];
  int t = threadIdx.x;
  int blk = blockIdx.x;
  int img = blk >> 1;
  int half = blk & 1;
  {
    const float* src = &patches[(size_t)img*3072];
    for (int e=t; e<3072; e+=256){
      int ci = e >> 10;
      int rem = e & 1023;
      int iy = rem >> 5, ix = rem & 31;
      in_l[ci*1056 + iy*33 + ix] = src[e];
    }
  }
  for (int e=t; e<1200; e+=256){
    w_t[e] = wT[(e>>4)*32 + half*16 + (e&15)];
  }
  if (t<16){ int c=half*16+t; pb[t]=cb[c]; ps[t]=bng[c]*rsqrtf(1.f+1e-5f); psh[t]=bnb[c]; }
  __syncthreads();
  int oy = t>>4, ox = t&15;
  float acc[16];
  #pragma unroll
  for (int i=0;i<16;++i) acc[i]=0.f;
  for (int ci=0; ci<3; ++ci){
    const float* inb = &in_l[ci*1056];
    #pragma unroll
    for (int ky=0; ky<5; ++ky){
      int iy = oy*2-2+ky;
      bool vy = (iy>=0)&&(iy<32);
      #pragma unroll
      for (int kx=0; kx<5; ++kx){
        int ix = ox*2-2+kx;
        bool vx = (ix>=0)&&(ix<32);
        float v = (vx&&vy) ? inb[iy*33+ix] : 0.f;
        const float* wr = &w_t[(ci*25+ky*5+kx)*16];
        #pragma unroll
        for (int cg=0; cg<4; ++cg){
          float4 wv = *(const float4*)&wr[cg*4];
          acc[cg*4+0]+=v*wv.x; acc[cg*4+1]+=v*wv.y; acc[cg*4+2]+=v*wv.z; acc[cg*4+3]+=v*wv.w;
        }
      }
    }
  }
  // NHWC write: h1[img][pix=t][ci = half*16 + c]
  u16* ob = &h1[(size_t)img*8192 + (size_t)t*32 + half*16];
  #pragma unroll
  for (int c=0;c<16;++c){
    float y = (acc[c]+pb[c])*ps[c]+psh[c];
    ob[c] = f2bf(gelu_f(y));
  }
}

// ---------------------------------------------------------------------------
// MFMA implicit-GEMM 3x3 s2 p1 conv: NHWC bf16 in -> NHWC bf16 out (or pooled)
// A: rows = (img,opix), k = ci (masked ds_read_b128 from swizzled LDS)
// B: w_pack[tap][co][ci] staged per tap (conv2: all taps)
// C/D (m89): col = lane&15, row = (lane>>4)*4 + reg
// ---------------------------------------------------------------------------
template<int CI,int CO,int IH,int OH,int WAVES,int MT,int SA1,int SA2,int SW1,int POOL>
__global__ __launch_bounds__(WAVES*64) void convm_k(const u16* __restrict__ hin,
    const u16* __restrict__ wp, const float* __restrict__ cb,
    const float* __restrict__ bng, const float* __restrict__ bnb,
    u16* __restrict__ hout, float* __restrict__ pooled)
{
  constexpr int OPIX = OH*OH, IPIX = IH*IH;
  constexpr int NT = CO/16, KS = CI/32;
  constexpr int ROWS = WAVES*MT*16;
  constexpr int IMG = ROWS/OPIX;
  constexpr int IMGB = IPIX*CI*2;
  constexpr bool PRE = (CO==64);
  constexpr int TH = WAVES*64;
  constexpr int OPSH = (OPIX==64)?6:((OPIX==16)?4:2);
  constexpr int OHSH = (OH==8)?3:((OH==4)?2:1);

  __shared__ u16 in_l[IMG*IPIX*CI];
  __shared__ u16 w_l[(PRE?9:1)*CO*CI];

  int t = threadIdx.x, blk = blockIdx.x;
  int lane = t & 63, wv = t >> 6;
  int lr = lane & 15, g = lane >> 4;

  { // stage input (NHWC, swizzled)
    const uint4* src = (const uint4*)(hin + (size_t)blk*IMG*IPIX*CI);
    constexpr int CH = IMG*IPIX*CI/8;
    for (int e=t; e<CH; e+=TH){
      uint4 v = src[e];
      *(uint4*)((char*)in_l + swz<SA1,SA2>((u32)e*16u)) = v;
    }
  }
  if (PRE){
    const uint4* src = (const uint4*)wp;
    constexpr int CH = 9*CO*CI/8;
    for (int e=t; e<CH; e+=TH){
      uint4 v = src[e];
      *(uint4*)((char*)w_l + swz<SW1,0>((u32)e*16u)) = v;
    }
  }
  __syncthreads();

  int oyv[MT], oxv[MT], ibv[MT];
  #pragma unroll
  for (int mt=0; mt<MT; ++mt){
    int rl = wv*(MT*16) + mt*16 + lr;
    int imgl = rl >> OPSH;
    int opix = rl & (OPIX-1);
    oyv[mt] = opix >> OHSH;
    oxv[mt] = opix & (OH-1);
    ibv[mt] = imgl*IMGB;
  }

  f32x4 acc[MT][NT];
  #pragma unroll
  for (int mt=0;mt<MT;++mt)
    #pragma unroll
    for (int nt=0;nt<NT;++nt) acc[mt][nt] = (f32x4){0.f,0.f,0.f,0.f};

  for (int tap=0; tap<9; ++tap){
    int ky = (tap<3)?0:((tap<6)?1:2);
    int kx = tap - ky*3;
    if (!PRE){
      __syncthreads();
      const uint4* src = (const uint4*)(wp + (size_t)tap*CO*CI);
      constexpr int CH = CO*CI/8;
      for (int e=t; e<CH; e+=TH){
        uint4 v = src[e];
        *(uint4*)((char*)w_l + swz<SW1,0>((u32)e*16u)) = v;
      }
      __syncthreads();
    }
    const u16* wl = w_l + (PRE ? tap*CO*CI : 0);
    #pragma unroll
    for (int ks=0; ks<KS; ++ks){
      bf16x8 af[MT];
      #pragma unroll
      for (int mt=0; mt<MT; ++mt){
        int iy = 2*oyv[mt] - 1 + ky;
        int ix = 2*oxv[mt] - 1 + kx;
        bf16x8 a = {};
        if (iy>=0 && iy<IH && ix>=0 && ix<IH){
          u32 b = (u32)(ibv[mt] + (iy*IH+ix)*CI*2 + ks*64 + g*16);
          a = *(const bf16x8*)((const char*)in_l + swz<SA1,SA2>(b));
        }
        af[mt] = a;
      }
      bf16x8 bfr[NT];
      #pragma unroll
      for (int nt=0; nt<NT; ++nt){
        u32 b = (u32)((nt*16+lr)*CI*2 + ks*64 + g*16);
        bfr[nt] = *(const bf16x8*)((const char*)wl + swz<SW1,0>(b));
      }
      #pragma unroll
      for (int nt=0; nt<NT; ++nt)
        #pragma unroll
        for (int mt=0; mt<MT; ++mt)
          acc[mt][nt] = __builtin_amdgcn_mfma_f32_16x16x32_bf16(af[mt], bfr[nt], acc[mt][nt], 0, 0, 0);
    }
  }

  if (!POOL){
    #pragma unroll
    for (int nt=0; nt<NT; ++nt){
      int co = nt*16 + lr;
      float S = bng[co]*rsqrtf(1.f+1e-5f);
      float T = cb[co]*S + bnb[co];
      #pragma unroll
      for (int mt=0; mt<MT; ++mt){
        #pragma unroll
        for (int j=0;j<4;++j){
          int rl = wv*(MT*16) + mt*16 + g*4 + j;
          int imgl = rl >> OPSH, opix = rl & (OPIX-1);
          float y = gelu_f(acc[mt][nt][j]*S + T);
          hout[((size_t)(blk*IMG + imgl)*OPIX + opix)*CO + co] = f2bf(y);
        }
      }
    }
  } else {
    // conv4 fused 2x2 mean-pool: lane group g = image, regs = 4 opix
    #pragma unroll
    for (int nt=0; nt<NT; ++nt){
      int co = nt*16 + lr;
      float S = bng[co]*rsqrtf(1.f+1e-5f);
      float T = cb[co]*S + bnb[co];
      float s = 0.f;
      #pragma unroll
      for (int j=0;j<4;++j) s += gelu_f(acc[0][nt][j]*S + T);
      int n = blk*IMG + wv*4 + g;
      pooled[(size_t)n*CO + co] = 0.25f*s;
    }
  }
}

// ---------------------------------------------------------------------------
// fused GEMM: C[8192,256] = A@W^T (+A2@W2^T) + bias (+gated bias2) (+coords)
// MODE 0: plain   MODE 1: +coords cols (pj_w[:,256:258])   MODE 2: dual K
// ---------------------------------------------------------------------------
template<int MODE>
__global__ __launch_bounds__(256) void gemm_k(const float* __restrict__ A, const float* __restrict__ W,
   const float* __restrict__ bias, int ldw,
   const float* __restrict__ A2, const float* __restrict__ W2, const float* __restrict__ bias2,
   const int* __restrict__ deg, const float* __restrict__ coords, const float* __restrict__ pjw,
   float* __restrict__ C)
{
  __shared__ float a_l[32*16];
  __shared__ float b_l[32*256];
  int t=threadIdx.x; int row0=blockIdx.x*16;
  int tm=t>>6, tn=t&63;
  float acc[4][4];
  #pragma unroll
  for (int i=0;i<4;++i)
    #pragma unroll
    for (int j=0;j<4;++j) acc[i][j]=0.f;
  const int passes = (MODE==2)?2:1;
  for (int ps2=0; ps2<passes; ++ps2){
    const float* Ap = ps2? A2:A; const float* Wp = ps2? W2:W; int ld = ps2?256:ldw;
    for (int k0=0;k0<256;k0+=32){
      {
        int e=t*2; int r=e>>5; int k=e&31;
        float2 v = *(const float2*)&Ap[(size_t)(row0+r)*256 + k0+k];
        a_l[k*16+r]=v.x; a_l[(k+1)*16+r]=v.y;
      }
      {
        const float* wr = &Wp[(size_t)t*ld + k0];
        #pragma unroll
        for (int kk=0;kk<32;kk+=2){ float2 v = *(const float2*)&wr[kk]; b_l[kk*256+t]=v.x; b_l[(kk+1)*256+t]=v.y; }
      }
      __syncthreads();
      #pragma unroll
      for (int k=0;k<32;++k){
        float4 av = *(const float4*)&a_l[k*16+tm*4];
        float4 bv = *(const float4*)&b_l[k*256+tn*4];
        float aa[4]={av.x,av.y,av.z,av.w};
        float bb[4]={bv.x,bv.y,bv.z,bv.w};
        #pragma unroll
        for (int i=0;i<4;++i)
          #pragma unroll
          for (int j=0;j<4;++j) acc[i][j]+=aa[i]*bb[j];
      }
      __syncthreads();
    }
  }
  float4 bv = *(const float4*)&bias[tn*4];
  float bias4[4]={bv.x,bv.y,bv.z,bv.w};
  float b24[4]={0.f,0.f,0.f,0.f};
  float cw0[4], cw1[4];
  if (MODE==2){
    float4 b2 = *(const float4*)&bias2[tn*4];
    b24[0]=b2.x; b24[1]=b2.y; b24[2]=b2.z; b24[3]=b2.w;
  }
  if (MODE==1){
    #pragma unroll
    for (int j=0;j<4;++j){ cw0[j]=pjw[(size_t)(tn*4+j)*258+256]; cw1[j]=pjw[(size_t)(tn*4+j)*258+257]; }
  }
  #pragma unroll
  for (int i=0;i<4;++i){
    int r = row0 + tm*4 + i;
    float g2 = 0.f, c0=0.f, c1=0.f;
    if (MODE==2) g2 = (deg[r]>0)?1.f:0.f;
    if (MODE==1){ c0 = coords[(size_t)r*2]*1e-4f; c1 = coords[(size_t)r*2+1]*1e-4f; }
    float4 o;
    float vals[4];
    #pragma unroll
    for (int j=0;j<4;++j){
      float v = acc[i][j] + bias4[j];
      if (MODE==2) v += g2*b24[j];
      if (MODE==1) v += c0*cw0[j] + c1*cw1[j];
      vals[j]=v;
    }
    o.x=vals[0]; o.y=vals[1]; o.z=vals[2]; o.w=vals[3];
    *(float4*)&C[(size_t)r*256 + tn*4] = o;
  }
}

// ---------------------------------------------------------------------------
// LayerNorm variants. MODE 0: out = gelu(LN(tin))  MODE 1: out = LN(x + gelu(tin))
// ---------------------------------------------------------------------------
template<int MODE>
__global__ __launch_bounds__(256) void ln_k(const float* __restrict__ xin, const float* __restrict__ tin,
  const float* __restrict__ g, const float* __restrict__ b, float* __restrict__ out)
{
  int row = blockIdx.x, t = threadIdx.x;
  size_t o = (size_t)row*256+t;
  float v;
  if (MODE==0) v = tin[o];
  else v = xin[o] + gelu_f(tin[o]);
  float s = v, sq = v*v;
  #pragma unroll
  for (int off=32; off>=1; off>>=1){ s += __shfl_xor(s,off); sq += __shfl_xor(sq,off); }
  __shared__ float red[8];
  int wv = t>>6;
  if ((t&63)==0){ red[wv*2]=s; red[wv*2+1]=sq; }
  __syncthreads();
  s = red[0]+red[2]+red[4]+red[6];
  sq = red[1]+red[3]+red[5]+red[7];
  float mu = s*(1.f/256.f);
  float var = sq*(1.f/256.f) - mu*mu;
  float rs = rsqrtf(var + 1e-5f);
  float y = (v-mu)*rs*g[t] + b[t];
  if (MODE==0) y = gelu_f(y);
  out[o] = y;
}

// ---------------------------------------------------------------------------
// CSR build + gather-mean
// ---------------------------------------------------------------------------
__global__ __launch_bounds__(256) void degcount_k(const int* __restrict__ dst, int* __restrict__ deg){
  int e = blockIdx.x*256+threadIdx.x;
  if (e<E_) atomicAdd(&deg[dst[e]],1);
}

__global__ __launch_bounds__(256) void scan_k(const int* __restrict__ deg, int* __restrict__ rowptr,
  float* __restrict__ invd)
{
  __shared__ int part[256];
  int t = threadIdx.x;
  int base = t*32; int run=0; int loc[32];
  #pragma unroll
  for (int i=0;i<32;++i){ loc[i]=run; run += deg[base+i]; }
  part[t]=run;
  __syncthreads();
  for (int off=1; off<256; off<<=1){
    int v = (t>=off)? part[t-off] : 0;
    __syncthreads();
    part[t]+=v;
    __syncthreads();
  }
  int pre = (t>0)? part[t-1] : 0;
  #pragma unroll
  for (int i=0;i<32;++i){
    rowptr[base+i] = pre + loc[i];
    int dv = deg[base+i];
    invd[base+i] = 1.f/fmaxf((float)dv,1.f);
  }
  if (t==255) rowptr[N_] = part[255];
}

__global__ __launch_bounds__(256) void fill_k(const int* __restrict__ src, const int* __restrict__ dst,
  const int* __restrict__ rowptr, int* __restrict__ cursor, int* __restrict__ colidx)
{
  int e = blockIdx.x*256+threadIdx.x;
  if (e<E_){
    int d = dst[e];
    int pos = rowptr[d] + atomicAdd(&cursor[d],1);
    colidx[pos] = src[e];
  }
}

__global__ __launch_bounds__(256) void gather_k(const float* __restrict__ x, const int* __restrict__ rowptr,
    const int* __restrict__ colidx, const float* __restrict__ invd, float* __restrict__ xbar)
{
  int d = blockIdx.x, t = threadIdx.x;
  int j0 = rowptr[d], j1 = rowptr[d+1];
  float s = 0.f;
  for (int j=j0;j<j1;++j){ int c = colidx[j]; s += x[(size_t)c*256+t]; }
  xbar[(size_t)d*256+t] = s*invd[d];
}

// ---------------------------------------------------------------------------
// heads: comp(8) / cmpo(16) / prog(32) from final x
// ---------------------------------------------------------------------------
__global__ __launch_bounds__(64) void heads_k(const float* __restrict__ x,
  const float* __restrict__ cw, const float* __restrict__ cbs,
  const float* __restrict__ mw, const float* __restrict__ mbs,
  const float* __restrict__ pw, const float* __restrict__ pbs,
  float* __restrict__ out)
{
  __shared__ float xr[256];
  int row = blockIdx.x, t = threadIdx.x;
  *(float4*)&xr[t*4] = *(const float4*)&x[(size_t)row*256 + t*4];
  __syncthreads();
  if (t>=56) return;
  const float* w; float bb; float* op;
  if (t<8){ w=&cw[t*256]; bb=cbs[t]; op = out + 2097152 + (size_t)row*8 + t; }
  else if (t<24){ int q=t-8; w=&mw[q*256]; bb=mbs[q]; op = out + 2162688 + (size_t)row*16 + q; }
  else { int q=t-24; w=&pw[q*256]; bb=pbs[q]; op = out + 2293760 + (size_t)row*32 + q; }
  float acc=0.f;
  #pragma unroll 8
  for (int k=0;k<256;k+=4){
    float4 xv=*(const float4*)&xr[k];
    float4 wv=*(const float4*)&w[k];
    acc += xv.x*wv.x + xv.y*wv.y + xv.z*wv.z + xv.w*wv.w;
  }
  *op = acc + bb;
}

// ---------------------------------------------------------------------------
// launch
// ---------------------------------------------------------------------------
extern "C" void kernel_launch(void* const* d_in, const int* in_sizes, int n_in,
                              void* d_out, int out_size, void* d_ws, size_t ws_size,
                              hipStream_t stream)
{
  const float* patches = (const float*)d_in[0];
  const float* coords  = (const float*)d_in[1];
  const int*   eidx    = (const int*)d_in[2];
  const float* c1w = (const float*)d_in[3];  const float* c1b = (const float*)d_in[4];
  const float* b1g = (const float*)d_in[5];  const float* b1b = (const float*)d_in[6];
  const float* c2w = (const float*)d_in[7];  const float* c2b = (const float*)d_in[8];
  const float* b2g = (const float*)d_in[9];  const float* b2b = (const float*)d_in[10];
  const float* c3w = (const float*)d_in[11]; const float* c3b = (const float*)d_in[12];
  const float* b3g = (const float*)d_in[13]; const float* b3b = (const float*)d_in[14];
  const float* c4w = (const float*)d_in[15]; const float* c4b = (const float*)d_in[16];
  const float* b4g = (const float*)d_in[17]; const float* b4b = (const float*)d_in[18];
  const float* encw = (const float*)d_in[19]; const float* encb = (const float*)d_in[20];
  const float* pjw  = (const float*)d_in[21]; const float* pjb  = (const float*)d_in[22];
  const float* plng = (const float*)d_in[23]; const float* plnb = (const float*)d_in[24];
  const float* msgw = (const float*)d_in[25]; const float* msgb = (const float*)d_in[26];
  const float* spw  = (const float*)d_in[27]; const float* spb  = (const float*)d_in[28];
  const float* lng  = (const float*)d_in[29]; const float* lnb  = (const float*)d_in[30];
  const float* compw = (const float*)d_in[31]; const float* compb = (const float*)d_in[32];
  const float* cmpow = (const float*)d_in[33]; const float* cmpob = (const float*)d_in[34];
  const float* progw = (const float*)d_in[35]; const float* progb = (const float*)d_in[36];
  float* out = (float*)d_out;
  char* ws = (char*)d_ws;

  const size_t OFF_H1   = 0;                    // 134217728 bytes (bf16 NHWC)
  const size_t OFF_H2   = 134217728;            // 67108864 (NHWC)
  const size_t OFF_H3   = 201326592;            // 33554432 (NHWC)
  const size_t OFF_POOL = 234881024;            // 8388608
  const size_t OFF_IMGF = 243269632;            // 8388608
  const size_t OFF_TBUF = 251658240;            // 8388608
  const size_t OFF_XA   = 260046848;            // 8388608
  const size_t OFF_XB   = 268435456;            // 8388608
  const size_t OFF_XBAR = 276824064;            // 8388608
  const size_t OFF_DEG  = 285212672;            // 32768
  const size_t OFF_ROWP = 285245440;            // 65536
  const size_t OFF_CURS = 285310976;            // 32768
  const size_t OFF_COL  = 285343744;            // 524288
  const size_t OFF_INVD = 285868032;            // 32768
  // packed conv weights live in the TBUF window; dead before first tbuf use
  const size_t OFF_WP4  = OFF_TBUF;             // 589824 (bf16)
  const size_t OFF_WP3  = OFF_TBUF + 589824;    // 147456
  const size_t OFF_WP2  = OFF_TBUF + 737280;    // 36864
  const size_t OFF_WT1  = OFF_TBUF + 774144;    // 9600 (f32)

  u16* h1 = (u16*)(ws+OFF_H1);
  u16* h2 = (u16*)(ws+OFF_H2);
  u16* h3 = (u16*)(ws+OFF_H3);
  float* pooled = (float*)(ws+OFF_POOL);
  float* imgf = (float*)(ws+OFF_IMGF);
  float* tbuf = (float*)(ws+OFF_TBUF);
  float* xa = (float*)(ws+OFF_XA);
  float* xb = (float*)(ws+OFF_XB);
  float* xbar = (float*)(ws+OFF_XBAR);
  int* deg = (int*)(ws+OFF_DEG);
  int* rowp = (int*)(ws+OFF_ROWP);
  int* curs = (int*)(ws+OFF_CURS);
  int* col = (int*)(ws+OFF_COL);
  float* invd = (float*)(ws+OFF_INVD);
  float* wt1 = (float*)(ws+OFF_WT1);
  u16* wp2 = (u16*)(ws+OFF_WP2);
  u16* wp3 = (u16*)(ws+OFF_WP3);
  u16* wp4 = (u16*)(ws+OFF_WP4);

  hipMemsetAsync(deg, 0, 32768, stream);
  hipMemsetAsync(curs, 0, 32768, stream);

  wtrans_k<<<(2400+255)/256,256,0,stream>>>(c1w, wt1, 75, 32, 2400);
  wpack_k<<<(18432+255)/256,256,0,stream>>>(c2w, wp2, 64, 32, 18432);
  wpack_k<<<(73728+255)/256,256,0,stream>>>(c3w, wp3, 128, 64, 73728);
  wpack_k<<<(294912+255)/256,256,0,stream>>>(c4w, wp4, 256, 128, 294912);

  conv1_k<<<16384,256,0,stream>>>(patches, wt1, c1b, b1g, b1b, h1);
  // conv2: CI=32 CO=64 IH=16 OH=8, 8 waves x MT2 -> 4 img/block, swzA S1=7, W S1=7
  convm_k<32,64,16,8,8,2,7,0,7,0><<<2048,512,0,stream>>>(h1, wp2, c2b, b2g, b2b, h2, nullptr);
  // conv3: CI=64 CO=128 IH=8 OH=4, 4 waves x MT2 -> 8 img/block, swzA (8,11), W S1=7
  convm_k<64,128,8,4,4,2,8,11,7,0><<<1024,256,0,stream>>>(h2, wp3, c3b, b3g, b3b, h3, nullptr);
  // conv4: CI=128 CO=256 IH=4 OH=2, 4 waves x MT1 -> 16 img/block, swzA (9,12), W S1=8, fused pool
  convm_k<128,256,4,2,4,1,9,12,8,1><<<512,256,0,stream>>>(h3, wp4, c4b, b4g, b4b, nullptr, pooled);

  gemm_k<0><<<512,256,0,stream>>>(pooled, encw, encb, 256, nullptr,nullptr,nullptr,nullptr,nullptr,nullptr, imgf);
  gemm_k<1><<<512,256,0,stream>>>(imgf, pjw, pjb, 258, nullptr,nullptr,nullptr,nullptr, coords, pjw, tbuf);
  ln_k<0><<<8192,256,0,stream>>>(tbuf, tbuf, plng, plnb, xa);

  degcount_k<<<512,256,0,stream>>>(eidx+E_, deg);
  scan_k<<<1,256,0,stream>>>(deg, rowp, invd);
  fill_k<<<512,256,0,stream>>>(eidx, eidx+E_, rowp, curs, col);

  float* xcur = xa;
  for (int i=0;i<4;++i){
    gather_k<<<8192,256,0,stream>>>(xcur, rowp, col, invd, xbar);
    gemm_k<2><<<512,256,0,stream>>>(xcur, spw+(size_t)i*65536, spb+(size_t)i*256, 256,
                                    xbar, msgw+(size_t)i*65536, msgb+(size_t)i*256,
                                    deg, nullptr, nullptr, tbuf);
    float* xnext = (i==3)? out : ((i&1)? xa : xb);
    ln_k<1><<<8192,256,0,stream>>>(xcur, tbuf, lng+(size_t)i*256, lnb+(size_t)i*256, xnext);
    xcur = xnext;
  }
  heads_k<<<8192,64,0,stream>>>(out, compw, compb, cmpow, cmpob, progw, progb, out);
}

// Round 7
// 1022.365 us; speedup vs baseline: 6.0126x; 1.7447x over previous
//
#include <hip/hip_runtime.h>
#include <hip/hip_bf16.h>

#define N_ 8192
#define E_ 131072

typedef unsigned short u16;
typedef unsigned int u32;
typedef __attribute__((ext_vector_type(8))) short bf16x8;
typedef __attribute__((ext_vector_type(4))) float f32x4;

__device__ __forceinline__ float bf2f(u16 u){ return __uint_as_float(((u32)u)<<16); }
__device__ __forceinline__ u16 f2bf(float f){
  u32 u = __float_as_uint(f);
  u32 r = (u + 0x7fffu + ((u>>16)&1u)) >> 16;
  return (u16)r;
}
__device__ __forceinline__ float gelu_f(float x){ return 0.5f*x*(1.f+erff(x*0.70710678118654752f)); }

// XOR-swizzle: permute byte bits 4-6 keyed on bits >=7 (involution; 16B-chunk preserving)
template<int S1,int S2>
__device__ __forceinline__ u32 swz(u32 b){
  if (S1==0) return b;
  u32 k = b >> S1;
  if (S2) k ^= (b >> S2);
  return b ^ ((k & 7u) << 4);
}

// ---------------------------------------------------------------------------
// conv1 weight pack: f32 [co][ci*25+tap] -> bf16 [co][104] with kk = ci*32+tap
// (tap slots 25..31 and kk 96..103 zeroed -> zero-weight absorbs A garbage)
// ---------------------------------------------------------------------------
__global__ __launch_bounds__(256) void wpack1_k(const float* __restrict__ src,
    u16* __restrict__ dst)
{
  int e = blockIdx.x*256 + threadIdx.x;
  if (e < 3328){
    int co = e / 104, r = e - co*104;
    int ci = r >> 5, tap = r & 31;
    u16 v = 0;
    if (ci < 3 && tap < 25) v = f2bf(src[co*75 + ci*25 + tap]);
    dst[e] = v;
  }
}

// ---------------------------------------------------------------------------
// weight pack (conv2/3/4): f32 OIHW [co][ci][tap9] -> bf16 [tap][co][ci]
// ---------------------------------------------------------------------------
__global__ __launch_bounds__(256) void wpack_k(const float* __restrict__ src,
    u16* __restrict__ dst, int CO, int CI, int total)
{
  int e = blockIdx.x*256 + threadIdx.x;
  if (e < total){
    int tap = e / (CO*CI);
    int rem = e - tap*CO*CI;
    int co = rem / CI, ci = rem - co*CI;
    dst[e] = f2bf(src[((size_t)co*CI + ci)*9 + tap]);
  }
}

// ---------------------------------------------------------------------------
// conv1 MFMA: [N,3,32,32] f32 -> h1 NHWC [N][256][32] bf16, k5 s2 p2 +BN+GELU
// block = 1 image, 4 waves x 4 m-tiles. A = im2col-in-registers from
// halo-staged bf16 image (no bounds masks); B = wpack1 [co][104].
// K layout kk = ci*32+tap; invalid taps read garbage x zero weight = 0.
// ---------------------------------------------------------------------------
__global__ __launch_bounds__(256) void conv1m_k(const float* __restrict__ patches,
    const u16* __restrict__ wp, const float* __restrict__ cb,
    const float* __restrict__ bng, const float* __restrict__ bnb,
    u16* __restrict__ h1)
{
  // [0,4000): image halo frame, [ci][36 rows][37 cols]; [4000,7328): weights
  __shared__ __align__(16) u16 sbuf[4000 + 3328];
  int t = threadIdx.x;
  int img = blockIdx.x;

  for (int e=t; e<2000; e+=256) ((u32*)sbuf)[e] = 0;          // zero image region
  {
    const uint4* s4 = (const uint4*)wp;
    uint4* d4 = (uint4*)(sbuf + 4000);
    for (int e=t; e<416; e+=256) d4[e] = s4[e];               // stage weights
  }
  __syncthreads();
  {
    const float* src = patches + (size_t)img*3072;
    for (int e=t; e<3072; e+=256){
      int ci = e >> 10, rem = e & 1023, iy = rem >> 5, ix = rem & 31;
      sbuf[ci*1332 + (iy+2)*37 + (ix+2)] = f2bf(src[e]);
    }
  }
  __syncthreads();

  int lane = t & 63, wv = t >> 6;
  int lr = lane & 15, g = lane >> 4;

  int roff[8];                       // per-lane byte offsets for taps g*8+j
  #pragma unroll
  for (int j=0;j<8;++j){
    int tap = g*8 + j;
    int ty = (tap*13) >> 6;          // floor(tap/5) for tap<25; safe garbage else
    int tx = tap - ty*5;
    roff[j] = ty*74 + tx*2;
  }

  int pixb[4];
  #pragma unroll
  for (int mt=0;mt<4;++mt){
    int row = wv*64 + mt*16 + lr;
    int oy = row >> 4, ox = row & 15;
    pixb[mt] = oy*148 + ox*4;        // byte offset of (2oy, 2ox) in halo frame
  }

  f32x4 acc[4][2];
  #pragma unroll
  for (int mt=0;mt<4;++mt){
    acc[mt][0] = (f32x4){0.f,0.f,0.f,0.f};
    acc[mt][1] = (f32x4){0.f,0.f,0.f,0.f};
  }

  #pragma unroll
  for (int ks=0; ks<3; ++ks){        // ks = ci
    bf16x8 bfr[2];
    #pragma unroll
    for (int nt=0;nt<2;++nt){
      u32 b = (u32)((nt*16+lr)*208 + ks*64 + g*16);
      bfr[nt] = *(const bf16x8*)((const char*)(sbuf+4000) + b);
    }
    #pragma unroll
    for (int mt=0;mt<4;++mt){
      union { bf16x8 v; u16 s[8]; } a;
      const char* base = (const char*)sbuf + ks*2664 + pixb[mt];
      #pragma unroll
      for (int j=0;j<8;++j) a.s[j] = *(const u16*)(base + roff[j]);
      acc[mt][0] = __builtin_amdgcn_mfma_f32_16x16x32_bf16(a.v, bfr[0], acc[mt][0], 0,0,0);
      acc[mt][1] = __builtin_amdgcn_mfma_f32_16x16x32_bf16(a.v, bfr[1], acc[mt][1], 0,0,0);
    }
  }

  #pragma unroll
  for (int nt=0;nt<2;++nt){
    int co = nt*16 + lr;
    float S = bng[co]*rsqrtf(1.f+1e-5f);
    float T = cb[co]*S + bnb[co];
    #pragma unroll
    for (int mt=0;mt<4;++mt){
      #pragma unroll
      for (int j=0;j<4;++j){
        int opix = wv*64 + mt*16 + g*4 + j;
        h1[(size_t)img*8192 + opix*32 + co] = f2bf(gelu_f(acc[mt][nt][j]*S + T));
      }
    }
  }
}

// ---------------------------------------------------------------------------
// MFMA implicit-GEMM 3x3 s2 p1 conv: NHWC bf16 in -> NHWC bf16 out (or pooled)
// ---------------------------------------------------------------------------
template<int CI,int CO,int IH,int OH,int WAVES,int MT,int SA1,int SA2,int SW1,int POOL>
__global__ __launch_bounds__(WAVES*64) void convm_k(const u16* __restrict__ hin,
    const u16* __restrict__ wp, const float* __restrict__ cb,
    const float* __restrict__ bng, const float* __restrict__ bnb,
    u16* __restrict__ hout, float* __restrict__ pooled)
{
  constexpr int OPIX = OH*OH, IPIX = IH*IH;
  constexpr int NT = CO/16, KS = CI/32;
  constexpr int ROWS = WAVES*MT*16;
  constexpr int IMG = ROWS/OPIX;
  constexpr int IMGB = IPIX*CI*2;
  constexpr bool PRE = (CO==64);
  constexpr int TH = WAVES*64;
  constexpr int OPSH = (OPIX==64)?6:((OPIX==16)?4:2);
  constexpr int OHSH = (OH==8)?3:((OH==4)?2:1);

  __shared__ u16 in_l[IMG*IPIX*CI];
  __shared__ u16 w_l[(PRE?9:1)*CO*CI];

  int t = threadIdx.x, blk = blockIdx.x;
  int lane = t & 63, wv = t >> 6;
  int lr = lane & 15, g = lane >> 4;

  {
    const uint4* src = (const uint4*)(hin + (size_t)blk*IMG*IPIX*CI);
    constexpr int CH = IMG*IPIX*CI/8;
    for (int e=t; e<CH; e+=TH){
      uint4 v = src[e];
      *(uint4*)((char*)in_l + swz<SA1,SA2>((u32)e*16u)) = v;
    }
  }
  if (PRE){
    const uint4* src = (const uint4*)wp;
    constexpr int CH = 9*CO*CI/8;
    for (int e=t; e<CH; e+=TH){
      uint4 v = src[e];
      *(uint4*)((char*)w_l + swz<SW1,0>((u32)e*16u)) = v;
    }
  }
  __syncthreads();

  int oyv[MT], oxv[MT], ibv[MT];
  #pragma unroll
  for (int mt=0; mt<MT; ++mt){
    int rl = wv*(MT*16) + mt*16 + lr;
    int imgl = rl >> OPSH;
    int opix = rl & (OPIX-1);
    oyv[mt] = opix >> OHSH;
    oxv[mt] = opix & (OH-1);
    ibv[mt] = imgl*IMGB;
  }

  f32x4 acc[MT][NT];
  #pragma unroll
  for (int mt=0;mt<MT;++mt)
    #pragma unroll
    for (int nt=0;nt<NT;++nt) acc[mt][nt] = (f32x4){0.f,0.f,0.f,0.f};

  for (int tap=0; tap<9; ++tap){
    int ky = (tap<3)?0:((tap<6)?1:2);
    int kx = tap - ky*3;
    if (!PRE){
      __syncthreads();
      const uint4* src = (const uint4*)(wp + (size_t)tap*CO*CI);
      constexpr int CH = CO*CI/8;
      for (int e=t; e<CH; e+=TH){
        uint4 v = src[e];
        *(uint4*)((char*)w_l + swz<SW1,0>((u32)e*16u)) = v;
      }
      __syncthreads();
    }
    const u16* wl = w_l + (PRE ? tap*CO*CI : 0);
    #pragma unroll
    for (int ks=0; ks<KS; ++ks){
      bf16x8 af[MT];
      #pragma unroll
      for (int mt=0; mt<MT; ++mt){
        int iy = 2*oyv[mt] - 1 + ky;
        int ix = 2*oxv[mt] - 1 + kx;
        bf16x8 a = {};
        if (iy>=0 && iy<IH && ix>=0 && ix<IH){
          u32 b = (u32)(ibv[mt] + (iy*IH+ix)*CI*2 + ks*64 + g*16);
          a = *(const bf16x8*)((const char*)in_l + swz<SA1,SA2>(b));
        }
        af[mt] = a;
      }
      bf16x8 bfr[NT];
      #pragma unroll
      for (int nt=0; nt<NT; ++nt){
        u32 b = (u32)((nt*16+lr)*CI*2 + ks*64 + g*16);
        bfr[nt] = *(const bf16x8*)((const char*)wl + swz<SW1,0>(b));
      }
      #pragma unroll
      for (int nt=0; nt<NT; ++nt)
        #pragma unroll
        for (int mt=0; mt<MT; ++mt)
          acc[mt][nt] = __builtin_amdgcn_mfma_f32_16x16x32_bf16(af[mt], bfr[nt], acc[mt][nt], 0, 0, 0);
    }
  }

  if (!POOL){
    #pragma unroll
    for (int nt=0; nt<NT; ++nt){
      int co = nt*16 + lr;
      float S = bng[co]*rsqrtf(1.f+1e-5f);
      float T = cb[co]*S + bnb[co];
      #pragma unroll
      for (int mt=0; mt<MT; ++mt){
        #pragma unroll
        for (int j=0;j<4;++j){
          int rl = wv*(MT*16) + mt*16 + g*4 + j;
          int imgl = rl >> OPSH, opix = rl & (OPIX-1);
          float y = gelu_f(acc[mt][nt][j]*S + T);
          hout[((size_t)(blk*IMG + imgl)*OPIX + opix)*CO + co] = f2bf(y);
        }
      }
    }
  } else {
    #pragma unroll
    for (int nt=0; nt<NT; ++nt){
      int co = nt*16 + lr;
      float S = bng[co]*rsqrtf(1.f+1e-5f);
      float T = cb[co]*S + bnb[co];
      float s = 0.f;
      #pragma unroll
      for (int j=0;j<4;++j) s += gelu_f(acc[0][nt][j]*S + T);
      int n = blk*IMG + wv*4 + g;
      pooled[(size_t)n*CO + co] = 0.25f*s;
    }
  }
}

// ---------------------------------------------------------------------------
// fused GEMM: C[8192,256] = A@W^T (+A2@W2^T) + bias (+gated bias2) (+coords)
// MODE 0: plain   MODE 1: +coords cols (pj_w[:,256:258])   MODE 2: dual K
// ---------------------------------------------------------------------------
template<int MODE>
__global__ __launch_bounds__(256) void gemm_k(const float* __restrict__ A, const float* __restrict__ W,
   const float* __restrict__ bias, int ldw,
   const float* __restrict__ A2, const float* __restrict__ W2, const float* __restrict__ bias2,
   const int* __restrict__ deg, const float* __restrict__ coords, const float* __restrict__ pjw,
   float* __restrict__ C)
{
  __shared__ float a_l[32*16];
  __shared__ float b_l[32*256];
  int t=threadIdx.x; int row0=blockIdx.x*16;
  int tm=t>>6, tn=t&63;
  float acc[4][4];
  #pragma unroll
  for (int i=0;i<4;++i)
    #pragma unroll
    for (int j=0;j<4;++j) acc[i][j]=0.f;
  const int passes = (MODE==2)?2:1;
  for (int ps2=0; ps2<passes; ++ps2){
    const float* Ap = ps2? A2:A; const float* Wp = ps2? W2:W; int ld = ps2?256:ldw;
    for (int k0=0;k0<256;k0+=32){
      {
        int e=t*2; int r=e>>5; int k=e&31;
        float2 v = *(const float2*)&Ap[(size_t)(row0+r)*256 + k0+k];
        a_l[k*16+r]=v.x; a_l[(k+1)*16+r]=v.y;
      }
      {
        const float* wr = &Wp[(size_t)t*ld + k0];
        #pragma unroll
        for (int kk=0;kk<32;kk+=2){ float2 v = *(const float2*)&wr[kk]; b_l[kk*256+t]=v.x; b_l[(kk+1)*256+t]=v.y; }
      }
      __syncthreads();
      #pragma unroll
      for (int k=0;k<32;++k){
        float4 av = *(const float4*)&a_l[k*16+tm*4];
        float4 bv = *(const float4*)&b_l[k*256+tn*4];
        float aa[4]={av.x,av.y,av.z,av.w};
        float bb[4]={bv.x,bv.y,bv.z,bv.w};
        #pragma unroll
        for (int i=0;i<4;++i)
          #pragma unroll
          for (int j=0;j<4;++j) acc[i][j]+=aa[i]*bb[j];
      }
      __syncthreads();
    }
  }
  float4 bv = *(const float4*)&bias[tn*4];
  float bias4[4]={bv.x,bv.y,bv.z,bv.w};
  float b24[4]={0.f,0.f,0.f,0.f};
  float cw0[4], cw1[4];
  if (MODE==2){
    float4 b2 = *(const float4*)&bias2[tn*4];
    b24[0]=b2.x; b24[1]=b2.y; b24[2]=b2.z; b24[3]=b2.w;
  }
  if (MODE==1){
    #pragma unroll
    for (int j=0;j<4;++j){ cw0[j]=pjw[(size_t)(tn*4+j)*258+256]; cw1[j]=pjw[(size_t)(tn*4+j)*258+257]; }
  }
  #pragma unroll
  for (int i=0;i<4;++i){
    int r = row0 + tm*4 + i;
    float g2 = 0.f, c0=0.f, c1=0.f;
    if (MODE==2) g2 = (deg[r]>0)?1.f:0.f;
    if (MODE==1){ c0 = coords[(size_t)r*2]*1e-4f; c1 = coords[(size_t)r*2+1]*1e-4f; }
    float4 o;
    float vals[4];
    #pragma unroll
    for (int j=0;j<4;++j){
      float v = acc[i][j] + bias4[j];
      if (MODE==2) v += g2*b24[j];
      if (MODE==1) v += c0*cw0[j] + c1*cw1[j];
      vals[j]=v;
    }
    o.x=vals[0]; o.y=vals[1]; o.z=vals[2]; o.w=vals[3];
    *(float4*)&C[(size_t)r*256 + tn*4] = o;
  }
}

// ---------------------------------------------------------------------------
// LayerNorm variants. MODE 0: out = gelu(LN(tin))  MODE 1: out = LN(x + gelu(tin))
// ---------------------------------------------------------------------------
template<int MODE>
__global__ __launch_bounds__(256) void ln_k(const float* __restrict__ xin, const float* __restrict__ tin,
  const float* __restrict__ g, const float* __restrict__ b, float* __restrict__ out)
{
  int row = blockIdx.x, t = threadIdx.x;
  size_t o = (size_t)row*256+t;
  float v;
  if (MODE==0) v = tin[o];
  else v = xin[o] + gelu_f(tin[o]);
  float s = v, sq = v*v;
  #pragma unroll
  for (int off=32; off>=1; off>>=1){ s += __shfl_xor(s,off); sq += __shfl_xor(sq,off); }
  __shared__ float red[8];
  int wv = t>>6;
  if ((t&63)==0){ red[wv*2]=s; red[wv*2+1]=sq; }
  __syncthreads();
  s = red[0]+red[2]+red[4]+red[6];
  sq = red[1]+red[3]+red[5]+red[7];
  float mu = s*(1.f/256.f);
  float var = sq*(1.f/256.f) - mu*mu;
  float rs = rsqrtf(var + 1e-5f);
  float y = (v-mu)*rs*g[t] + b[t];
  if (MODE==0) y = gelu_f(y);
  out[o] = y;
}

// ---------------------------------------------------------------------------
// CSR build + gather-mean
// ---------------------------------------------------------------------------
__global__ __launch_bounds__(256) void degcount_k(const int* __restrict__ dst, int* __restrict__ deg){
  int e = blockIdx.x*256+threadIdx.x;
  if (e<E_) atomicAdd(&deg[dst[e]],1);
}

__global__ __launch_bounds__(256) void scan_k(const int* __restrict__ deg, int* __restrict__ rowptr,
  float* __restrict__ invd)
{
  __shared__ int part[256];
  int t = threadIdx.x;
  int base = t*32; int run=0; int loc[32];
  #pragma unroll
  for (int i=0;i<32;++i){ loc[i]=run; run += deg[base+i]; }
  part[t]=run;
  __syncthreads();
  for (int off=1; off<256; off<<=1){
    int v = (t>=off)? part[t-off] : 0;
    __syncthreads();
    part[t]+=v;
    __syncthreads();
  }
  int pre = (t>0)? part[t-1] : 0;
  #pragma unroll
  for (int i=0;i<32;++i){
    rowptr[base+i] = pre + loc[i];
    int dv = deg[base+i];
    invd[base+i] = 1.f/fmaxf((float)dv,1.f);
  }
  if (t==255) rowptr[N_] = part[255];
}

__global__ __launch_bounds__(256) void fill_k(const int* __restrict__ src, const int* __restrict__ dst,
  const int* __restrict__ rowptr, int* __restrict__ cursor, int* __restrict__ colidx)
{
  int e = blockIdx.x*256+threadIdx.x;
  if (e<E_){
    int d = dst[e];
    int pos = rowptr[d] + atomicAdd(&cursor[d],1);
    colidx[pos] = src[e];
  }
}

__global__ __launch_bounds__(256) void gather_k(const float* __restrict__ x, const int* __restrict__ rowptr,
    const int* __restrict__ colidx, const float* __restrict__ invd, float* __restrict__ xbar)
{
  int d = blockIdx.x, t = threadIdx.x;
  int j0 = rowptr[d], j1 = rowptr[d+1];
  float s = 0.f;
  for (int j=j0;j<j1;++j){ int c = colidx[j]; s += x[(size_t)c*256+t]; }
  xbar[(size_t)d*256+t] = s*invd[d];
}

// ---------------------------------------------------------------------------
// heads: comp(8) / cmpo(16) / prog(32) from final x
// ---------------------------------------------------------------------------
__global__ __launch_bounds__(64) void heads_k(const float* __restrict__ x,
  const float* __restrict__ cw, const float* __restrict__ cbs,
  const float* __restrict__ mw, const float* __restrict__ mbs,
  const float* __restrict__ pw, const float* __restrict__ pbs,
  float* __restrict__ out)
{
  __shared__ float xr[256];
  int row = blockIdx.x, t = threadIdx.x;
  *(float4*)&xr[t*4] = *(const float4*)&x[(size_t)row*256 + t*4];
  __syncthreads();
  if (t>=56) return;
  const float* w; float bb; float* op;
  if (t<8){ w=&cw[t*256]; bb=cbs[t]; op = out + 2097152 + (size_t)row*8 + t; }
  else if (t<24){ int q=t-8; w=&mw[q*256]; bb=mbs[q]; op = out + 2162688 + (size_t)row*16 + q; }
  else { int q=t-24; w=&pw[q*256]; bb=pbs[q]; op = out + 2293760 + (size_t)row*32 + q; }
  float acc=0.f;
  #pragma unroll 8
  for (int k=0;k<256;k+=4){
    float4 xv=*(const float4*)&xr[k];
    float4 wv=*(const float4*)&w[k];
    acc += xv.x*wv.x + xv.y*wv.y + xv.z*wv.z + xv.w*wv.w;
  }
  *op = acc + bb;
}

// ---------------------------------------------------------------------------
// launch
// ---------------------------------------------------------------------------
extern "C" void kernel_launch(void* const* d_in, const int* in_sizes, int n_in,
                              void* d_out, int out_size, void* d_ws, size_t ws_size,
                              hipStream_t stream)
{
  const float* patches = (const float*)d_in[0];
  const float* coords  = (const float*)d_in[1];
  const int*   eidx    = (const int*)d_in[2];
  const float* c1w = (const float*)d_in[3];  const float* c1b = (const float*)d_in[4];
  const float* b1g = (const float*)d_in[5];  const float* b1b = (const float*)d_in[6];
  const float* c2w = (const float*)d_in[7];  const float* c2b = (const float*)d_in[8];
  const float* b2g = (const float*)d_in[9];  const float* b2b = (const float*)d_in[10];
  const float* c3w = (const float*)d_in[11]; const float* c3b = (const float*)d_in[12];
  const float* b3g = (const float*)d_in[13]; const float* b3b = (const float*)d_in[14];
  const float* c4w = (const float*)d_in[15]; const float* c4b = (const float*)d_in[16];
  const float* b4g = (const float*)d_in[17]; const float* b4b = (const float*)d_in[18];
  const float* encw = (const float*)d_in[19]; const float* encb = (const float*)d_in[20];
  const float* pjw  = (const float*)d_in[21]; const float* pjb  = (const float*)d_in[22];
  const float* plng = (const float*)d_in[23]; const float* plnb = (const float*)d_in[24];
  const float* msgw = (const float*)d_in[25]; const float* msgb = (const float*)d_in[26];
  const float* spw  = (const float*)d_in[27]; const float* spb  = (const float*)d_in[28];
  const float* lng  = (const float*)d_in[29]; const float* lnb  = (const float*)d_in[30];
  const float* compw = (const float*)d_in[31]; const float* compb = (const float*)d_in[32];
  const float* cmpow = (const float*)d_in[33]; const float* cmpob = (const float*)d_in[34];
  const float* progw = (const float*)d_in[35]; const float* progb = (const float*)d_in[36];
  float* out = (float*)d_out;
  char* ws = (char*)d_ws;

  const size_t OFF_H1   = 0;                    // 134217728 bytes (bf16 NHWC)
  const size_t OFF_H2   = 134217728;            // 67108864 (NHWC)
  const size_t OFF_H3   = 201326592;            // 33554432 (NHWC)
  const size_t OFF_POOL = 234881024;            // 8388608
  const size_t OFF_IMGF = 243269632;            // 8388608
  const size_t OFF_TBUF = 251658240;            // 8388608
  const size_t OFF_XA   = 260046848;            // 8388608
  const size_t OFF_XB   = 268435456;            // 8388608
  const size_t OFF_XBAR = 276824064;            // 8388608
  const size_t OFF_DEG  = 285212672;            // 32768
  const size_t OFF_ROWP = 285245440;            // 65536
  const size_t OFF_CURS = 285310976;            // 32768
  const size_t OFF_COL  = 285343744;            // 524288
  const size_t OFF_INVD = 285868032;            // 32768
  // packed conv weights live in the TBUF window; dead before first tbuf use
  const size_t OFF_WP4  = OFF_TBUF;             // 589824 (bf16)
  const size_t OFF_WP3  = OFF_TBUF + 589824;    // 147456
  const size_t OFF_WP2  = OFF_TBUF + 737280;    // 36864
  const size_t OFF_WP1  = OFF_TBUF + 774144;    // 6656 (bf16 [32][104])

  u16* h1 = (u16*)(ws+OFF_H1);
  u16* h2 = (u16*)(ws+OFF_H2);
  u16* h3 = (u16*)(ws+OFF_H3);
  float* pooled = (float*)(ws+OFF_POOL);
  float* imgf = (float*)(ws+OFF_IMGF);
  float* tbuf = (float*)(ws+OFF_TBUF);
  float* xa = (float*)(ws+OFF_XA);
  float* xb = (float*)(ws+OFF_XB);
  float* xbar = (float*)(ws+OFF_XBAR);
  int* deg = (int*)(ws+OFF_DEG);
  int* rowp = (int*)(ws+OFF_ROWP);
  int* curs = (int*)(ws+OFF_CURS);
  int* col = (int*)(ws+OFF_COL);
  float* invd = (float*)(ws+OFF_INVD);
  u16* wp1 = (u16*)(ws+OFF_WP1);
  u16* wp2 = (u16*)(ws+OFF_WP2);
  u16* wp3 = (u16*)(ws+OFF_WP3);
  u16* wp4 = (u16*)(ws+OFF_WP4);

  hipMemsetAsync(deg, 0, 32768, stream);
  hipMemsetAsync(curs, 0, 32768, stream);

  wpack1_k<<<13,256,0,stream>>>(c1w, wp1);
  wpack_k<<<(18432+255)/256,256,0,stream>>>(c2w, wp2, 64, 32, 18432);
  wpack_k<<<(73728+255)/256,256,0,stream>>>(c3w, wp3, 128, 64, 73728);
  wpack_k<<<(294912+255)/256,256,0,stream>>>(c4w, wp4, 256, 128, 294912);

  conv1m_k<<<8192,256,0,stream>>>(patches, wp1, c1b, b1g, b1b, h1);
  // conv2: CI=32 CO=64 IH=16 OH=8, 8 waves x MT2 -> 4 img/block, swzA S1=7, W S1=7
  convm_k<32,64,16,8,8,2,7,0,7,0><<<2048,512,0,stream>>>(h1, wp2, c2b, b2g, b2b, h2, nullptr);
  // conv3: CI=64 CO=128 IH=8 OH=4, 4 waves x MT2 -> 8 img/block, swzA (8,11), W S1=7
  convm_k<64,128,8,4,4,2,8,11,7,0><<<1024,256,0,stream>>>(h2, wp3, c3b, b3g, b3b, h3, nullptr);
  // conv4: CI=128 CO=256 IH=4 OH=2, 4 waves x MT1 -> 16 img/block, swzA (9,12), W S1=8, fused pool
  convm_k<128,256,4,2,4,1,9,12,8,1><<<512,256,0,stream>>>(h3, wp4, c4b, b4g, b4b, nullptr, pooled);

  gemm_k<0><<<512,256,0,stream>>>(pooled, encw, encb, 256, nullptr,nullptr,nullptr,nullptr,nullptr,nullptr, imgf);
  gemm_k<1><<<512,256,0,stream>>>(imgf, pjw, pjb, 258, nullptr,nullptr,nullptr,nullptr, coords, pjw, tbuf);
  ln_k<0><<<8192,256,0,stream>>>(tbuf, tbuf, plng, plnb, xa);

  degcount_k<<<512,256,0,stream>>>(eidx+E_, deg);
  scan_k<<<1,256,0,stream>>>(deg, rowp, invd);
  fill_k<<<512,256,0,stream>>>(eidx, eidx+E_, rowp, curs, col);

  float* xcur = xa;
  for (int i=0;i<4;++i){
    gather_k<<<8192,256,0,stream>>>(xcur, rowp, col, invd, xbar);
    gemm_k<2><<<512,256,0,stream>>>(xcur, spw+(size_t)i*65536, spb+(size_t)i*256, 256,
                                    xbar, msgw+(size_t)i*65536, msgb+(size_t)i*256,
                                    deg, nullptr, nullptr, tbuf);
    float* xnext = (i==3)? out : ((i&1)? xa : xb);
    ln_k<1><<<8192,256,0,stream>>>(xcur, tbuf, lng+(size_t)i*256, lnb+(size_t)i*256, xnext);
    xcur = xnext;
  }
  heads_k<<<8192,64,0,stream>>>(out, compw, compb, cmpow, cmpob, progw, progb, out);
}